// Round 7
// baseline (651.141 us; speedup 1.0000x reference)
//
#include <hip/hip_runtime.h>
#include <hip/hip_bf16.h>

// RGCN 2-layer forward, MI355X.
// Two-phase edge flow: msg_kernel writes bf16 message rows (nontemporal, no
// atomics), reduce_kernel sums them per dst node via a dst-CSR (one wave per
// node). Per-relation W_r = comp@V (bf16, col-major W^T image), edges
// counting-sorted by etype (contention-free chunked sort). Self-loop GEMM via
// MFMA with a bf16 loop_w^T image. Fallback atomic path if d_ws is small.

typedef unsigned short u16;
typedef unsigned int   u32;
typedef __bf16 bf16x8 __attribute__((ext_vector_type(8)));
typedef float  f32x4  __attribute__((ext_vector_type(4)));
typedef u32    u32x2  __attribute__((ext_vector_type(2)));

#define N_NODES 15000
#define N_EDGES 400000
#define N_RELS  237
#define N_BASES 100
#define NT_MAX  1800   // sum ceil(n_r/256) <= 400000/256 + 237 = 1799.5
#define NB_SORT 196    // sort chunks
#define CHUNK   2048   // NB_SORT*CHUNK = 401408 >= N_EDGES

__device__ __forceinline__ u32 packbf(float a, float b) {
    u16 lo = __builtin_bit_cast(u16, (__bf16)a);
    u16 hi = __builtin_bit_cast(u16, (__bf16)b);
    return (u32)lo | ((u32)hi << 16);
}
__device__ __forceinline__ float bfbits2f(u32 hi16) {   // hi16 in low 16 bits
    u32 x = hi16 << 16;
    return __builtin_bit_cast(float, x);
}

// -------------------------------------------------- pass A: block histogram
__global__ __launch_bounds__(256) void histA_kernel(const int* __restrict__ etype,
                                                    int* __restrict__ blockHist) {
    __shared__ int hh[256];
    int tid = threadIdx.x, b = blockIdx.x;
    hh[tid] = 0;
    __syncthreads();
    int e0 = b * CHUNK;
    int e1 = e0 + CHUNK; if (e1 > N_EDGES) e1 = N_EDGES;
    for (int e = e0 + tid; e < e1; e += 256)
        atomicAdd(&hh[etype[e]], 1);
    __syncthreads();
    if (tid < N_RELS) blockHist[tid * NB_SORT + b] = hh[tid];
}

// ------------------- pass B: totals, prefix, tiles, per-block base offsets
__global__ __launch_bounds__(256) void scanB_kernel(const int* __restrict__ blockHist,
                                                    int* __restrict__ baseOff,
                                                    int2* __restrict__ tiles,
                                                    int* __restrict__ tileCount) {
    __shared__ int h[256], o[256], to[256];
    int tid = threadIdx.x;
    int sum = 0;
    if (tid < N_RELS)
        for (int b = 0; b < NB_SORT; ++b) sum += blockHist[tid * NB_SORT + b];
    h[tid] = (tid < N_RELS) ? sum : 0;
    __syncthreads();
    if (tid == 0) {
        int run = 0, tc = 0;
        for (int r = 0; r < N_RELS; ++r) {
            o[r] = run; run += h[r];
            to[r] = tc; tc += (h[r] + 255) >> 8;
        }
        *tileCount = tc;
    }
    __syncthreads();
    if (tid < N_RELS) {
        int n = h[tid], t0 = to[tid], base = o[tid];
        for (int t = 0; t * 256 < n; ++t) {
            int nE = n - t * 256; if (nE > 256) nE = 256;
            tiles[t0 + t] = make_int2(base + t * 256, (tid << 9) | nE);
        }
        int run = base;
        for (int b = 0; b < NB_SORT; ++b) {
            baseOff[tid * NB_SORT + b] = run;
            run += blockHist[tid * NB_SORT + b];
        }
    }
}

// ------------------------------- pass C: scatter with LDS cursors per block
__global__ __launch_bounds__(256) void scatterC_kernel(const int* __restrict__ etype,
                                                       const int* __restrict__ baseOff,
                                                       int* __restrict__ perm) {
    __shared__ int lcur[256];
    int tid = threadIdx.x, b = blockIdx.x;
    if (tid < N_RELS) lcur[tid] = baseOff[tid * NB_SORT + b];
    __syncthreads();
    int e0 = b * CHUNK;
    int e1 = e0 + CHUNK; if (e1 > N_EDGES) e1 = N_EDGES;
    for (int e = e0 + tid; e < e1; e += 256) {
        int r = etype[e];
        int pos = atomicAdd(&lcur[r], 1);
        perm[pos] = e;
    }
}

// ----------------------------------------- dst-CSR build (for reduce pass)
__global__ __launch_bounds__(256) void zeroDeg_kernel(int* __restrict__ deg) {
    int i = blockIdx.x * 256 + threadIdx.x;
    if (i < N_NODES) deg[i] = 0;
}
__global__ __launch_bounds__(256) void degcnt_kernel(const int* __restrict__ dst,
                                                     int* __restrict__ deg) {
    for (int e = blockIdx.x * 256 + threadIdx.x; e < N_EDGES; e += gridDim.x * 256)
        atomicAdd(&deg[dst[e]], 1);
}
__global__ __launch_bounds__(256) void scanDeg_kernel(const int* __restrict__ deg,
                                                      int* __restrict__ rowptr,
                                                      int* __restrict__ cursor) {
    __shared__ int part[256];
    int tid = threadIdx.x;
    const int R = 59;                       // 256*59 = 15104 >= 15001
    int lo = tid * R, hi = lo + R; if (hi > N_NODES + 1) hi = N_NODES + 1;
    int s = 0;
    for (int i = lo; i < hi; ++i) s += (i < N_NODES) ? deg[i] : 0;
    part[tid] = s;
    __syncthreads();
    if (tid == 0) {
        int run = 0;
        for (int t = 0; t < 256; ++t) { int tmp = part[t]; part[t] = run; run += tmp; }
    }
    __syncthreads();
    int run = part[tid];
    for (int i = lo; i < hi; ++i) {
        rowptr[i] = run; cursor[i] = run;
        run += (i < N_NODES) ? deg[i] : 0;
    }
}
__global__ __launch_bounds__(256) void scatterDst_kernel(const int* __restrict__ dst,
                                                         const int* __restrict__ perm,
                                                         int* __restrict__ cursor,
                                                         int* __restrict__ dstSlots) {
    for (int s = blockIdx.x * 256 + threadIdx.x; s < N_EDGES; s += gridDim.x * 256) {
        int e = perm[s];
        int v = dst[e];
        int pos = atomicAdd(&cursor[v], 1);   // ~27 edges/node: low contention
        dstSlots[pos] = s;
    }
}

// --------------------------------------- W_r = comp @ V  (fp32 -> bf16 RM)
__global__ __launch_bounds__(256) void wgemm_kernel(const float* __restrict__ comp,
                                                    const float* __restrict__ V,
                                                    u16* __restrict__ outRM) {
    __shared__ float cls[128 * 33];   // [b][rr] padded
    __shared__ float vls[32 * 256];   // [bb][n]
    int tid = threadIdx.x;
    int r0 = blockIdx.x * 32, n0 = blockIdx.y * 256;
    for (int idx = tid; idx < 32 * 128; idx += 256) {
        int rr = idx >> 7, b = idx & 127;
        float v = 0.f;
        if (b < N_BASES && (r0 + rr) < N_RELS) v = comp[(size_t)(r0 + rr) * N_BASES + b];
        cls[b * 33 + rr] = v;
    }
    float acc[4][8];
    #pragma unroll
    for (int i = 0; i < 4; ++i)
        #pragma unroll
        for (int j = 0; j < 8; ++j) acc[i][j] = 0.f;
    int rgrp = tid >> 5, ngrp = tid & 31;
    for (int bc = 0; bc < 4; ++bc) {
        __syncthreads();
        for (int idx = tid; idx < 32 * 256; idx += 256) {
            int bb = idx >> 8, n = idx & 255;
            int b = bc * 32 + bb;
            vls[idx] = (b < N_BASES) ? V[(size_t)b * 16384 + n0 + n] : 0.f;
        }
        __syncthreads();
        #pragma unroll 4
        for (int bb = 0; bb < 32; ++bb) {
            float a_[4];
            #pragma unroll
            for (int i = 0; i < 4; ++i) a_[i] = cls[(bc * 32 + bb) * 33 + rgrp * 4 + i];
            float4 b0 = *(const float4*)&vls[bb * 256 + ngrp * 8];
            float4 b1 = *(const float4*)&vls[bb * 256 + ngrp * 8 + 4];
            #pragma unroll
            for (int i = 0; i < 4; ++i) {
                acc[i][0] += a_[i] * b0.x; acc[i][1] += a_[i] * b0.y;
                acc[i][2] += a_[i] * b0.z; acc[i][3] += a_[i] * b0.w;
                acc[i][4] += a_[i] * b1.x; acc[i][5] += a_[i] * b1.y;
                acc[i][6] += a_[i] * b1.z; acc[i][7] += a_[i] * b1.w;
            }
        }
    }
    #pragma unroll
    for (int i = 0; i < 4; ++i) {
        int r = r0 + rgrp * 4 + i;
        if (r < N_RELS) {
            bf16x8 pk;
            #pragma unroll
            for (int j = 0; j < 8; ++j) pk[j] = (__bf16)acc[i][j];
            *(bf16x8*)(outRM + (size_t)r * 16384 + n0 + ngrp * 8) = pk;
        }
    }
}

// ----------------- transpose W (RM bf16) -> LINEAR col-major W^T image
// out uint index (per r): col*64 + kk2, value = {W[2k][col], W[2k+1][col]}
__global__ __launch_bounds__(256) void transp_kernel(const u16* __restrict__ in,
                                                     u16* __restrict__ outT) {
    __shared__ u16 tls[128 * 130];
    int r = blockIdx.x, tid = threadIdx.x;
    const u32* inu = (const u32*)(in + (size_t)r * 16384);
    #pragma unroll
    for (int i = 0; i < 32; ++i) {
        int idx = i * 256 + tid;           // 8192 uints: k = idx>>6, jpair = idx&63
        u32 v = inu[idx];
        int k = idx >> 6, jp = idx & 63;
        tls[k * 130 + jp * 2]     = (u16)(v & 0xffffu);
        tls[k * 130 + jp * 2 + 1] = (u16)(v >> 16);
    }
    __syncthreads();
    u32* outu = (u32*)(outT + (size_t)r * 16384);
    #pragma unroll
    for (int i = 0; i < 32; ++i) {
        int idx = i * 256 + tid;           // col = idx>>6, kk2 = idx&63
        int col = idx >> 6, kk2 = idx & 63;
        u32 v = (u32)tls[(2 * kk2) * 130 + col] | ((u32)tls[(2 * kk2 + 1) * 130 + col] << 16);
        outu[col * 64 + kk2] = v;
    }
}

// ---------- loop_w (fp32 RM [k][n]) -> bf16 col-major W^T image (linear)
__global__ __launch_bounds__(256) void loopT_kernel(const float* __restrict__ lw,
                                                    u16* __restrict__ outT) {
    int tid = threadIdx.x;
    u32* outu = (u32*)outT;
    #pragma unroll
    for (int i = 0; i < 32; ++i) {
        int idx = i * 256 + tid;           // col = idx>>6, kk2 = idx&63
        int col = idx >> 6, kk2 = idx & 63;
        float a = lw[(size_t)(2 * kk2) * 128 + col];
        float b = lw[(size_t)(2 * kk2 + 1) * 128 + col];
        outu[col * 64 + kk2] = packbf(a, b);
    }
}

// ------------- h = bias + f(x) @ loop_w  (MFMA, consecutive rows, f=relu)
__global__ __launch_bounds__(256) void init_mfma_kernel(const float* __restrict__ xin,
                                                        const u16* __restrict__ lwT,
                                                        const float* __restrict__ bias,
                                                        float* __restrict__ hout,
                                                        int reluIn) {
    __shared__ u16 xlds[8192];    // 16KB: [s][k] swizzled, 64 rows
    int v0 = blockIdx.x * 64;
    int tid = threadIdx.x, lane = tid & 63, w = tid >> 6;

    bf16x8 bfr[2][4];
    #pragma unroll
    for (int n2 = 0; n2 < 2; ++n2) {
        int col = w * 32 + n2 * 16 + (lane & 15);
        #pragma unroll
        for (int ks = 0; ks < 4; ++ks) {
            int k0 = ks * 32 + (lane >> 4) * 8;
            bfr[n2][ks] = *(const bf16x8*)(lwT + (size_t)col * 128 + k0);
        }
    }

    {
        int s = tid >> 2, p = tid & 3;
        int row = v0 + s;
        if (row < N_NODES) {
            const float4* xr = (const float4*)(xin + (size_t)row * 128 + p * 32);
            #pragma unroll
            for (int c = 0; c < 4; ++c) {
                float4 f0 = xr[c * 2], f1 = xr[c * 2 + 1];
                if (reluIn) {
                    f0.x = fmaxf(f0.x, 0.f); f0.y = fmaxf(f0.y, 0.f);
                    f0.z = fmaxf(f0.z, 0.f); f0.w = fmaxf(f0.w, 0.f);
                    f1.x = fmaxf(f1.x, 0.f); f1.y = fmaxf(f1.y, 0.f);
                    f1.z = fmaxf(f1.z, 0.f); f1.w = fmaxf(f1.w, 0.f);
                }
                bf16x8 pk;
                pk[0] = (__bf16)f0.x; pk[1] = (__bf16)f0.y;
                pk[2] = (__bf16)f0.z; pk[3] = (__bf16)f0.w;
                pk[4] = (__bf16)f1.x; pk[5] = (__bf16)f1.y;
                pk[6] = (__bf16)f1.z; pk[7] = (__bf16)f1.w;
                int ch = p * 4 + c;
                *(bf16x8*)((char*)xlds + s * 256 + ((ch * 16) ^ ((s & 7) << 4))) = pk;
            }
        } else {
            bf16x8 z = {(__bf16)0.f, (__bf16)0.f, (__bf16)0.f, (__bf16)0.f,
                        (__bf16)0.f, (__bf16)0.f, (__bf16)0.f, (__bf16)0.f};
            #pragma unroll
            for (int c = 0; c < 4; ++c) {
                int ch = p * 4 + c;
                *(bf16x8*)((char*)xlds + s * 256 + ((ch * 16) ^ ((s & 7) << 4))) = z;
            }
        }
    }
    __syncthreads();

    #pragma unroll
    for (int rt = 0; rt < 4; ++rt) {
        bf16x8 af[4];
        int arow = rt * 16 + (lane & 15);
        #pragma unroll
        for (int ks = 0; ks < 4; ++ks) {
            int k0 = ks * 32 + (lane >> 4) * 8;
            af[ks] = *(const bf16x8*)((const char*)xlds + arow * 256 + ((k0 * 2) ^ ((arow & 7) << 4)));
        }
        f32x4 acc[2];
        acc[0] = (f32x4){0.f, 0.f, 0.f, 0.f};
        acc[1] = (f32x4){0.f, 0.f, 0.f, 0.f};
        #pragma unroll
        for (int ks = 0; ks < 4; ++ks) {
            acc[0] = __builtin_amdgcn_mfma_f32_16x16x32_bf16(bfr[0][ks], af[ks], acc[0], 0, 0, 0);
            acc[1] = __builtin_amdgcn_mfma_f32_16x16x32_bf16(bfr[1][ks], af[ks], acc[1], 0, 0, 0);
        }
        int orow = v0 + rt * 16 + (lane & 15);
        if (orow < N_NODES) {
            #pragma unroll
            for (int n2 = 0; n2 < 2; ++n2) {
                int fbase = w * 32 + n2 * 16 + ((lane >> 4) << 2);
                float4 bv = *(const float4*)(bias + fbase);
                float4 o;
                o.x = acc[n2][0] + bv.x; o.y = acc[n2][1] + bv.y;
                o.z = acc[n2][2] + bv.z; o.w = acc[n2][3] + bv.w;
                *(float4*)(hout + (size_t)orow * 128 + fbase) = o;
            }
        }
    }
}

// --------------------------------- phase 1: per-edge messages (no atomics)
// block = one (relation, <=256-edge chunk); 4 waves; W^T frags direct from
// global; x subtiles gathered into XOR-swizzled LDS; SWAPPED mfma(bf, af) so
// each lane holds 4 consecutive features of one edge -> packed bf16 8B
// NONTEMPORAL stores to msg[slot][128] (keeps x/W resident in L2/L3).
__global__ __launch_bounds__(256) void msg_kernel(const float* __restrict__ x,
                                                  const int* __restrict__ src,
                                                  const float* __restrict__ norm,
                                                  const int* __restrict__ perm,
                                                  const int2* __restrict__ tiles,
                                                  const int* __restrict__ tileCount,
                                                  const u16* __restrict__ WbtT,
                                                  u16* __restrict__ msg,
                                                  int reluIn) {
    __shared__ u16 xlds[8192];    // 16KB: [s][k] swizzled
    int bid = blockIdx.x;
    if (bid >= *tileCount) return;
    int2 td = tiles[bid];
    int slot0 = td.x;
    int r  = td.y >> 9;
    int nE = td.y & 511;
    int tid = threadIdx.x, lane = tid & 63, w = tid >> 6;

    bf16x8 bfr[2][4];
    #pragma unroll
    for (int n2 = 0; n2 < 2; ++n2) {
        int col = w * 32 + n2 * 16 + (lane & 15);
        #pragma unroll
        for (int ks = 0; ks < 4; ++ks) {
            int k0 = ks * 32 + (lane >> 4) * 8;
            bfr[n2][ks] = *(const bf16x8*)(WbtT + (size_t)r * 16384 + col * 128 + k0);
        }
    }

    for (int s0 = 0; s0 < nE; s0 += 64) {
        int cnt = nE - s0; if (cnt > 64) cnt = 64;
        __syncthreads();   // previous subtile's xlds reads complete
        {
            int s = tid >> 2, p = tid & 3;
            if (s < cnt) {
                int e = perm[slot0 + s0 + s];
                int xrow = src[e];
                float nm = norm[e];
                const float4* xr = (const float4*)(x + (size_t)xrow * 128 + p * 32);
                #pragma unroll
                for (int c = 0; c < 4; ++c) {
                    float4 f0 = xr[c * 2], f1 = xr[c * 2 + 1];
                    if (reluIn) {
                        f0.x = fmaxf(f0.x, 0.f); f0.y = fmaxf(f0.y, 0.f);
                        f0.z = fmaxf(f0.z, 0.f); f0.w = fmaxf(f0.w, 0.f);
                        f1.x = fmaxf(f1.x, 0.f); f1.y = fmaxf(f1.y, 0.f);
                        f1.z = fmaxf(f1.z, 0.f); f1.w = fmaxf(f1.w, 0.f);
                    }
                    bf16x8 pk;
                    pk[0] = (__bf16)(f0.x * nm); pk[1] = (__bf16)(f0.y * nm);
                    pk[2] = (__bf16)(f0.z * nm); pk[3] = (__bf16)(f0.w * nm);
                    pk[4] = (__bf16)(f1.x * nm); pk[5] = (__bf16)(f1.y * nm);
                    pk[6] = (__bf16)(f1.z * nm); pk[7] = (__bf16)(f1.w * nm);
                    int ch = p * 4 + c;
                    *(bf16x8*)((char*)xlds + s * 256 + ((ch * 16) ^ ((s & 7) << 4))) = pk;
                }
            } else {
                bf16x8 z = {(__bf16)0.f, (__bf16)0.f, (__bf16)0.f, (__bf16)0.f,
                            (__bf16)0.f, (__bf16)0.f, (__bf16)0.f, (__bf16)0.f};
                #pragma unroll
                for (int c = 0; c < 4; ++c) {
                    int ch = p * 4 + c;
                    *(bf16x8*)((char*)xlds + s * 256 + ((ch * 16) ^ ((s & 7) << 4))) = z;
                }
            }
        }
        __syncthreads();

        #pragma unroll
        for (int rt = 0; rt < 4; ++rt) {
            bf16x8 af[4];
            int arow = rt * 16 + (lane & 15);
            #pragma unroll
            for (int ks = 0; ks < 4; ++ks) {
                int k0 = ks * 32 + (lane >> 4) * 8;
                af[ks] = *(const bf16x8*)((const char*)xlds + arow * 256 + ((k0 * 2) ^ ((arow & 7) << 4)));
            }
            f32x4 acc[2];
            acc[0] = (f32x4){0.f, 0.f, 0.f, 0.f};
            acc[1] = (f32x4){0.f, 0.f, 0.f, 0.f};
            #pragma unroll
            for (int ks = 0; ks < 4; ++ks) {
                acc[0] = __builtin_amdgcn_mfma_f32_16x16x32_bf16(bfr[0][ks], af[ks], acc[0], 0, 0, 0);
                acc[1] = __builtin_amdgcn_mfma_f32_16x16x32_bf16(bfr[1][ks], af[ks], acc[1], 0, 0, 0);
            }
            int srow = rt * 16 + (lane & 15);
            if (srow < cnt) {
                int slot = slot0 + s0 + srow;
                #pragma unroll
                for (int n2 = 0; n2 < 2; ++n2) {
                    int fbase = w * 32 + n2 * 16 + ((lane >> 4) << 2);
                    u32x2 pk;
                    pk.x = packbf(acc[n2][0], acc[n2][1]);
                    pk.y = packbf(acc[n2][2], acc[n2][3]);
                    __builtin_nontemporal_store(pk, (u32x2*)(msg + (size_t)slot * 128 + fbase));
                }
            }
        }
    }
}

// ---------------------------- phase 2: per-node reduce (one wave per node)
__global__ __launch_bounds__(256) void reduce_kernel(const u32* __restrict__ msg32,
                                                     const int* __restrict__ rowptr,
                                                     const int* __restrict__ dstSlots,
                                                     float* __restrict__ h) {
    int v = blockIdx.x * 4 + (threadIdx.x >> 6);
    int lane = threadIdx.x & 63;
    if (v >= N_NODES) return;
    int p0 = rowptr[v], p1 = rowptr[v + 1];
    float a0 = 0.f, a1 = 0.f, b0 = 0.f, b1 = 0.f;
    int j = p0;
    for (; j + 1 < p1; j += 2) {
        int s0 = dstSlots[j], s1 = dstSlots[j + 1];
        u32 m0 = __builtin_nontemporal_load(msg32 + (size_t)s0 * 64 + lane);
        u32 m1 = __builtin_nontemporal_load(msg32 + (size_t)s1 * 64 + lane);
        a0 += bfbits2f(m0 & 0xffffu); a1 += bfbits2f(m0 >> 16);
        b0 += bfbits2f(m1 & 0xffffu); b1 += bfbits2f(m1 >> 16);
    }
    if (j < p1) {
        int s0 = dstSlots[j];
        u32 m0 = __builtin_nontemporal_load(msg32 + (size_t)s0 * 64 + lane);
        a0 += bfbits2f(m0 & 0xffffu); a1 += bfbits2f(m0 >> 16);
    }
    float2 hv = *(float2*)(h + (size_t)v * 128 + lane * 2);
    hv.x += a0 + b0;
    hv.y += a1 + b1;
    *(float2*)(h + (size_t)v * 128 + lane * 2) = hv;
}

// ------------------- fallback: fused edge GEMM + fp32 atomic scatter
__global__ __launch_bounds__(256) void edge_atomic_kernel(const float* __restrict__ x,
                                                          const int* __restrict__ src,
                                                          const int* __restrict__ dst,
                                                          const float* __restrict__ norm,
                                                          const int* __restrict__ perm,
                                                          const int2* __restrict__ tiles,
                                                          const int* __restrict__ tileCount,
                                                          const u16* __restrict__ WbtT,
                                                          float* __restrict__ hout,
                                                          int reluIn) {
    __shared__ u16 xlds[8192];
    __shared__ int dlds[64];
    int bid = blockIdx.x;
    if (bid >= *tileCount) return;
    int2 td = tiles[bid];
    int slot0 = td.x;
    int r  = td.y >> 9;
    int nE = td.y & 511;
    int tid = threadIdx.x, lane = tid & 63, w = tid >> 6;

    bf16x8 bfr[2][4];
    #pragma unroll
    for (int n2 = 0; n2 < 2; ++n2) {
        int col = w * 32 + n2 * 16 + (lane & 15);
        #pragma unroll
        for (int ks = 0; ks < 4; ++ks) {
            int k0 = ks * 32 + (lane >> 4) * 8;
            bfr[n2][ks] = *(const bf16x8*)(WbtT + (size_t)r * 16384 + col * 128 + k0);
        }
    }

    for (int s0 = 0; s0 < nE; s0 += 64) {
        int cnt = nE - s0; if (cnt > 64) cnt = 64;
        __syncthreads();
        {
            int s = tid >> 2, p = tid & 3;
            if (s < cnt) {
                int e = perm[slot0 + s0 + s];
                int xrow = src[e];
                float nm = norm[e];
                if (p == 0) dlds[s] = dst[e];
                const float4* xr = (const float4*)(x + (size_t)xrow * 128 + p * 32);
                #pragma unroll
                for (int c = 0; c < 4; ++c) {
                    float4 f0 = xr[c * 2], f1 = xr[c * 2 + 1];
                    if (reluIn) {
                        f0.x = fmaxf(f0.x, 0.f); f0.y = fmaxf(f0.y, 0.f);
                        f0.z = fmaxf(f0.z, 0.f); f0.w = fmaxf(f0.w, 0.f);
                        f1.x = fmaxf(f1.x, 0.f); f1.y = fmaxf(f1.y, 0.f);
                        f1.z = fmaxf(f1.z, 0.f); f1.w = fmaxf(f1.w, 0.f);
                    }
                    bf16x8 pk;
                    pk[0] = (__bf16)(f0.x * nm); pk[1] = (__bf16)(f0.y * nm);
                    pk[2] = (__bf16)(f0.z * nm); pk[3] = (__bf16)(f0.w * nm);
                    pk[4] = (__bf16)(f1.x * nm); pk[5] = (__bf16)(f1.y * nm);
                    pk[6] = (__bf16)(f1.z * nm); pk[7] = (__bf16)(f1.w * nm);
                    int ch = p * 4 + c;
                    *(bf16x8*)((char*)xlds + s * 256 + ((ch * 16) ^ ((s & 7) << 4))) = pk;
                }
            } else {
                bf16x8 z = {(__bf16)0.f, (__bf16)0.f, (__bf16)0.f, (__bf16)0.f,
                            (__bf16)0.f, (__bf16)0.f, (__bf16)0.f, (__bf16)0.f};
                #pragma unroll
                for (int c = 0; c < 4; ++c) {
                    int ch = p * 4 + c;
                    *(bf16x8*)((char*)xlds + s * 256 + ((ch * 16) ^ ((s & 7) << 4))) = z;
                }
            }
        }
        __syncthreads();

        #pragma unroll
        for (int rt = 0; rt < 4; ++rt) {
            bf16x8 af[4];
            int arow = rt * 16 + (lane & 15);
            #pragma unroll
            for (int ks = 0; ks < 4; ++ks) {
                int k0 = ks * 32 + (lane >> 4) * 8;
                af[ks] = *(const bf16x8*)((const char*)xlds + arow * 256 + ((k0 * 2) ^ ((arow & 7) << 4)));
            }
            f32x4 acc[2];
            acc[0] = (f32x4){0.f, 0.f, 0.f, 0.f};
            acc[1] = (f32x4){0.f, 0.f, 0.f, 0.f};
            #pragma unroll
            for (int ks = 0; ks < 4; ++ks) {
                acc[0] = __builtin_amdgcn_mfma_f32_16x16x32_bf16(bfr[0][ks], af[ks], acc[0], 0, 0, 0);
                acc[1] = __builtin_amdgcn_mfma_f32_16x16x32_bf16(bfr[1][ks], af[ks], acc[1], 0, 0, 0);
            }
            int srow = rt * 16 + (lane & 15);
            if (srow < cnt) {
                int d = dlds[srow];
                #pragma unroll
                for (int n2 = 0; n2 < 2; ++n2) {
                    float* hp = hout + (size_t)d * 128 + w * 32 + n2 * 16 + ((lane >> 4) << 2);
                    #pragma unroll
                    for (int reg = 0; reg < 4; ++reg) atomicAdd(hp + reg, acc[n2][reg]);
                }
            }
        }
    }
}

// ------------------------------------------------------------------ launch
extern "C" void kernel_launch(void* const* d_in, const int* in_sizes, int n_in,
                              void* d_out, int out_size, void* d_ws, size_t ws_size,
                              hipStream_t stream) {
    const int*   src   = (const int*)  d_in[1];
    const int*   dst   = (const int*)  d_in[2];
    const int*   etype = (const int*)  d_in[3];
    const float* norm  = (const float*)d_in[4];
    const float* emb   = (const float*)d_in[6];
    const float* V1    = (const float*)d_in[7];
    const float* comp1 = (const float*)d_in[8];
    const float* loop1 = (const float*)d_in[9];
    const float* bias1 = (const float*)d_in[10];
    const float* V2    = (const float*)d_in[11];
    const float* comp2 = (const float*)d_in[12];
    const float* loop2 = (const float*)d_in[13];
    const float* bias2 = (const float*)d_in[14];
    float* out = (float*)d_out;

    char* ws = (char*)d_ws;
    size_t off = 0;
    auto carve = [&](size_t bytes) -> void* {
        void* p = ws + off;
        off += (bytes + 255) & ~(size_t)255;
        return p;
    };
    const size_t WB = (size_t)N_RELS * 16384 * 2;                 // 7.77 MB
    u16* Wbt1      = (u16*)carve(WB);
    u16* Wbt2      = (u16*)carve(WB);
    void* uni      = carve(WB);                                   // union: rm / h1
    u16*   rm      = (u16*)uni;
    float* h1      = (float*)uni;
    int*  perm     = (int*)carve((size_t)N_EDGES * 4);
    int*  blockHist= (int*)carve((size_t)N_RELS * NB_SORT * 4);
    int*  baseOff  = (int*)carve((size_t)N_RELS * NB_SORT * 4);
    int2* tiles    = (int2*)carve((size_t)NT_MAX * 8);
    int*  tileCnt  = (int*)carve(256);
    u16*  lwT1     = (u16*)carve(128 * 128 * 2);
    u16*  lwT2     = (u16*)carve(128 * 128 * 2);
    int*  deg      = (int*)carve((size_t)N_NODES * 4);
    int*  rowptr   = (int*)carve((size_t)(N_NODES + 1) * 4);
    int*  cursor   = (int*)carve((size_t)(N_NODES + 1) * 4);
    int*  dstSlots = (int*)carve((size_t)N_EDGES * 4);
    u16*  msg      = (u16*)carve((size_t)N_EDGES * 128 * 2);      // 102.4 MB
    bool twoPhase = (off <= ws_size);                             // call-invariant

    // ---- sort edges by relation (shared by both layers), contention-free
    histA_kernel<<<NB_SORT, 256, 0, stream>>>(etype, blockHist);
    scanB_kernel<<<1, 256, 0, stream>>>(blockHist, baseOff, tiles, tileCnt);
    scatterC_kernel<<<NB_SORT, 256, 0, stream>>>(etype, baseOff, perm);

    if (twoPhase) {
        // ---- dst-CSR (slot lists per destination node)
        zeroDeg_kernel<<<59, 256, 0, stream>>>(deg);
        degcnt_kernel<<<391, 256, 0, stream>>>(dst, deg);
        scanDeg_kernel<<<1, 256, 0, stream>>>(deg, rowptr, cursor);
        scatterDst_kernel<<<391, 256, 0, stream>>>(dst, perm, cursor, dstSlots);
    }

    // ---- per-relation weights (bf16, linear col-major W^T image)
    dim3 wg(8, 64);
    wgemm_kernel<<<wg, 256, 0, stream>>>(comp1, V1, rm);
    transp_kernel<<<N_RELS, 256, 0, stream>>>(rm, Wbt1);
    wgemm_kernel<<<wg, 256, 0, stream>>>(comp2, V2, rm);
    transp_kernel<<<N_RELS, 256, 0, stream>>>(rm, Wbt2);
    loopT_kernel<<<1, 256, 0, stream>>>(loop1, lwT1);
    loopT_kernel<<<1, 256, 0, stream>>>(loop2, lwT2);

    if (twoPhase) {
        // ---- layer 1
        init_mfma_kernel<<<235, 256, 0, stream>>>(emb, lwT1, bias1, h1, 0);
        msg_kernel<<<NT_MAX, 256, 0, stream>>>(emb, src, norm, perm, tiles,
                                               tileCnt, Wbt1, msg, 0);
        reduce_kernel<<<3750, 256, 0, stream>>>((const u32*)msg, rowptr, dstSlots, h1);
        // ---- layer 2
        init_mfma_kernel<<<235, 256, 0, stream>>>(h1, lwT2, bias2, out, 1);
        msg_kernel<<<NT_MAX, 256, 0, stream>>>(h1, src, norm, perm, tiles,
                                               tileCnt, Wbt2, msg, 1);
        reduce_kernel<<<3750, 256, 0, stream>>>((const u32*)msg, rowptr, dstSlots, out);
    } else {
        // ---- fallback: fused atomic scatter (small workspace)
        init_mfma_kernel<<<235, 256, 0, stream>>>(emb, lwT1, bias1, h1, 0);
        edge_atomic_kernel<<<NT_MAX, 256, 0, stream>>>(emb, src, dst, norm, perm, tiles,
                                                       tileCnt, Wbt1, h1, 0);
        init_mfma_kernel<<<235, 256, 0, stream>>>(h1, lwT2, bias2, out, 1);
        edge_atomic_kernel<<<NT_MAX, 256, 0, stream>>>(h1, src, dst, norm, perm, tiles,
                                                       tileCnt, Wbt2, out, 1);
    }
}

// Round 8
// 486.038 us; speedup vs baseline: 1.3397x; 1.3397x over previous
//
#include <hip/hip_runtime.h>
#include <hip/hip_bf16.h>

// RGCN 2-layer forward, MI355X.
// Two-phase edge flow: msg_kernel writes unscaled bf16 message rows x@W_r
// (regular stores, no atomics); reduce_kernel sums norm_e * msg_e per dst
// node via a dst-CSR (one wave per node, 4-deep ILP). x pre-cast to bf16
// (relu folded) so the gather is 256B/row. Per-relation W_r = comp@V (bf16,
// col-major W^T image), edges counting-sorted by etype. XCD-aware tile
// swizzle keeps each relation's W in one XCD's L2. Fallback atomic path if
// d_ws is too small for the 102 MB message buffer.

typedef unsigned short u16;
typedef unsigned int   u32;
typedef __bf16 bf16x8 __attribute__((ext_vector_type(8)));
typedef float  f32x4  __attribute__((ext_vector_type(4)));
typedef u32    u32x2  __attribute__((ext_vector_type(2)));

#define N_NODES 15000
#define N_EDGES 400000
#define N_RELS  237
#define N_BASES 100
#define NT_MAX  1800   // 8 * 225, >= sum ceil(n_r/256) (max 1799)
#define NB_SORT 196    // sort chunks
#define CHUNK   2048   // NB_SORT*CHUNK = 401408 >= N_EDGES

__device__ __forceinline__ u32 packbf(float a, float b) {
    u16 lo = __builtin_bit_cast(u16, (__bf16)a);
    u16 hi = __builtin_bit_cast(u16, (__bf16)b);
    return (u32)lo | ((u32)hi << 16);
}
__device__ __forceinline__ float bfbits2f(u32 hi16) {   // hi16 in low 16 bits
    u32 x = hi16 << 16;
    return __builtin_bit_cast(float, x);
}

// -------------------------------------------------- pass A: block histogram
__global__ __launch_bounds__(256) void histA_kernel(const int* __restrict__ etype,
                                                    int* __restrict__ blockHist) {
    __shared__ int hh[256];
    int tid = threadIdx.x, b = blockIdx.x;
    hh[tid] = 0;
    __syncthreads();
    int e0 = b * CHUNK;
    int e1 = e0 + CHUNK; if (e1 > N_EDGES) e1 = N_EDGES;
    for (int e = e0 + tid; e < e1; e += 256)
        atomicAdd(&hh[etype[e]], 1);
    __syncthreads();
    if (tid < N_RELS) blockHist[tid * NB_SORT + b] = hh[tid];
}

// ------------------- pass B: totals, prefix, tiles, per-block base offsets
__global__ __launch_bounds__(256) void scanB_kernel(const int* __restrict__ blockHist,
                                                    int* __restrict__ baseOff,
                                                    int2* __restrict__ tiles,
                                                    int* __restrict__ tileCount) {
    __shared__ int h[256], o[256], to[256];
    int tid = threadIdx.x;
    int sum = 0;
    if (tid < N_RELS)
        for (int b = 0; b < NB_SORT; ++b) sum += blockHist[tid * NB_SORT + b];
    h[tid] = (tid < N_RELS) ? sum : 0;
    __syncthreads();
    if (tid == 0) {
        int run = 0, tc = 0;
        for (int r = 0; r < N_RELS; ++r) {
            o[r] = run; run += h[r];
            to[r] = tc; tc += (h[r] + 255) >> 8;
        }
        *tileCount = tc;
    }
    __syncthreads();
    if (tid < N_RELS) {
        int n = h[tid], t0 = to[tid], base = o[tid];
        for (int t = 0; t * 256 < n; ++t) {
            int nE = n - t * 256; if (nE > 256) nE = 256;
            tiles[t0 + t] = make_int2(base + t * 256, (tid << 9) | nE);
        }
        int run = base;
        for (int b = 0; b < NB_SORT; ++b) {
            baseOff[tid * NB_SORT + b] = run;
            run += blockHist[tid * NB_SORT + b];
        }
    }
}

// ----------- pass C: scatter with LDS cursors; also emit srcPerm/normPerm
__global__ __launch_bounds__(256) void scatterC_kernel(const int* __restrict__ etype,
                                                       const int* __restrict__ src,
                                                       const float* __restrict__ norm,
                                                       const int* __restrict__ baseOff,
                                                       int* __restrict__ perm,
                                                       int* __restrict__ srcPerm,
                                                       float* __restrict__ normPerm) {
    __shared__ int lcur[256];
    int tid = threadIdx.x, b = blockIdx.x;
    if (tid < N_RELS) lcur[tid] = baseOff[tid * NB_SORT + b];
    __syncthreads();
    int e0 = b * CHUNK;
    int e1 = e0 + CHUNK; if (e1 > N_EDGES) e1 = N_EDGES;
    for (int e = e0 + tid; e < e1; e += 256) {
        int r = etype[e];
        int pos = atomicAdd(&lcur[r], 1);
        perm[pos] = e;
        srcPerm[pos] = src[e];
        normPerm[pos] = norm[e];
    }
}

// ----------------------------------------- dst-CSR build (for reduce pass)
__global__ __launch_bounds__(256) void zeroDeg_kernel(int* __restrict__ deg) {
    int i = blockIdx.x * 256 + threadIdx.x;
    if (i < N_NODES) deg[i] = 0;
}
__global__ __launch_bounds__(256) void degcnt_kernel(const int* __restrict__ dst,
                                                     int* __restrict__ deg) {
    for (int e = blockIdx.x * 256 + threadIdx.x; e < N_EDGES; e += gridDim.x * 256)
        atomicAdd(&deg[dst[e]], 1);
}
__global__ __launch_bounds__(256) void scanDeg_kernel(const int* __restrict__ deg,
                                                      int* __restrict__ rowptr,
                                                      int* __restrict__ cursor) {
    __shared__ int part[256];
    int tid = threadIdx.x;
    const int R = 59;                       // 256*59 = 15104 >= 15001
    int lo = tid * R, hi = lo + R; if (hi > N_NODES + 1) hi = N_NODES + 1;
    int s = 0;
    for (int i = lo; i < hi; ++i) s += (i < N_NODES) ? deg[i] : 0;
    part[tid] = s;
    __syncthreads();
    if (tid == 0) {
        int run = 0;
        for (int t = 0; t < 256; ++t) { int tmp = part[t]; part[t] = run; run += tmp; }
    }
    __syncthreads();
    int run = part[tid];
    for (int i = lo; i < hi; ++i) {
        rowptr[i] = run; cursor[i] = run;
        run += (i < N_NODES) ? deg[i] : 0;
    }
}
__global__ __launch_bounds__(256) void scatterDst_kernel(const int* __restrict__ dst,
                                                         const int* __restrict__ perm,
                                                         int* __restrict__ cursor,
                                                         int* __restrict__ dstSlots) {
    for (int s = blockIdx.x * 256 + threadIdx.x; s < N_EDGES; s += gridDim.x * 256) {
        int e = perm[s];
        int v = dst[e];
        int pos = atomicAdd(&cursor[v], 1);   // ~27 edges/node: low contention
        dstSlots[pos] = s;
    }
}

// --------------------------------------- W_r = comp @ V  (fp32 -> bf16 RM)
__global__ __launch_bounds__(256) void wgemm_kernel(const float* __restrict__ comp,
                                                    const float* __restrict__ V,
                                                    u16* __restrict__ outRM) {
    __shared__ float cls[128 * 33];   // [b][rr] padded
    __shared__ float vls[32 * 256];   // [bb][n]
    int tid = threadIdx.x;
    int r0 = blockIdx.x * 32, n0 = blockIdx.y * 256;
    for (int idx = tid; idx < 32 * 128; idx += 256) {
        int rr = idx >> 7, b = idx & 127;
        float v = 0.f;
        if (b < N_BASES && (r0 + rr) < N_RELS) v = comp[(size_t)(r0 + rr) * N_BASES + b];
        cls[b * 33 + rr] = v;
    }
    float acc[4][8];
    #pragma unroll
    for (int i = 0; i < 4; ++i)
        #pragma unroll
        for (int j = 0; j < 8; ++j) acc[i][j] = 0.f;
    int rgrp = tid >> 5, ngrp = tid & 31;
    for (int bc = 0; bc < 4; ++bc) {
        __syncthreads();
        for (int idx = tid; idx < 32 * 256; idx += 256) {
            int bb = idx >> 8, n = idx & 255;
            int b = bc * 32 + bb;
            vls[idx] = (b < N_BASES) ? V[(size_t)b * 16384 + n0 + n] : 0.f;
        }
        __syncthreads();
        #pragma unroll 4
        for (int bb = 0; bb < 32; ++bb) {
            float a_[4];
            #pragma unroll
            for (int i = 0; i < 4; ++i) a_[i] = cls[(bc * 32 + bb) * 33 + rgrp * 4 + i];
            float4 b0 = *(const float4*)&vls[bb * 256 + ngrp * 8];
            float4 b1 = *(const float4*)&vls[bb * 256 + ngrp * 8 + 4];
            #pragma unroll
            for (int i = 0; i < 4; ++i) {
                acc[i][0] += a_[i] * b0.x; acc[i][1] += a_[i] * b0.y;
                acc[i][2] += a_[i] * b0.z; acc[i][3] += a_[i] * b0.w;
                acc[i][4] += a_[i] * b1.x; acc[i][5] += a_[i] * b1.y;
                acc[i][6] += a_[i] * b1.z; acc[i][7] += a_[i] * b1.w;
            }
        }
    }
    #pragma unroll
    for (int i = 0; i < 4; ++i) {
        int r = r0 + rgrp * 4 + i;
        if (r < N_RELS) {
            bf16x8 pk;
            #pragma unroll
            for (int j = 0; j < 8; ++j) pk[j] = (__bf16)acc[i][j];
            *(bf16x8*)(outRM + (size_t)r * 16384 + n0 + ngrp * 8) = pk;
        }
    }
}

// ----------------- transpose W (RM bf16) -> LINEAR col-major W^T image
// out uint index (per r): col*64 + kk2, value = {W[2k][col], W[2k+1][col]}
__global__ __launch_bounds__(256) void transp_kernel(const u16* __restrict__ in,
                                                     u16* __restrict__ outT) {
    __shared__ u16 tls[128 * 130];
    int r = blockIdx.x, tid = threadIdx.x;
    const u32* inu = (const u32*)(in + (size_t)r * 16384);
    #pragma unroll
    for (int i = 0; i < 32; ++i) {
        int idx = i * 256 + tid;           // 8192 uints: k = idx>>6, jpair = idx&63
        u32 v = inu[idx];
        int k = idx >> 6, jp = idx & 63;
        tls[k * 130 + jp * 2]     = (u16)(v & 0xffffu);
        tls[k * 130 + jp * 2 + 1] = (u16)(v >> 16);
    }
    __syncthreads();
    u32* outu = (u32*)(outT + (size_t)r * 16384);
    #pragma unroll
    for (int i = 0; i < 32; ++i) {
        int idx = i * 256 + tid;           // col = idx>>6, kk2 = idx&63
        int col = idx >> 6, kk2 = idx & 63;
        u32 v = (u32)tls[(2 * kk2) * 130 + col] | ((u32)tls[(2 * kk2 + 1) * 130 + col] << 16);
        outu[col * 64 + kk2] = v;
    }
}

// ---------- loop_w (fp32 RM [k][n]) -> bf16 col-major W^T image (linear)
__global__ __launch_bounds__(256) void loopT_kernel(const float* __restrict__ lw,
                                                    u16* __restrict__ outT) {
    int tid = threadIdx.x;
    u32* outu = (u32*)outT;
    #pragma unroll
    for (int i = 0; i < 32; ++i) {
        int idx = i * 256 + tid;           // col = idx>>6, kk2 = idx&63
        int col = idx >> 6, kk2 = idx & 63;
        float a = lw[(size_t)(2 * kk2) * 128 + col];
        float b = lw[(size_t)(2 * kk2 + 1) * 128 + col];
        outu[col * 64 + kk2] = packbf(a, b);
    }
}

// ------------------- x (fp32, optional relu) -> bf16 row image [v][128]
__global__ __launch_bounds__(256) void xbf_kernel(const float* __restrict__ x,
                                                  u16* __restrict__ xbf,
                                                  int reluIn) {
    int i = blockIdx.x * 256 + threadIdx.x;     // one thread = 8 features
    if (i >= N_NODES * 16) return;
    const float4* xp = (const float4*)x;
    float4 f0 = xp[i * 2], f1 = xp[i * 2 + 1];
    if (reluIn) {
        f0.x = fmaxf(f0.x, 0.f); f0.y = fmaxf(f0.y, 0.f);
        f0.z = fmaxf(f0.z, 0.f); f0.w = fmaxf(f0.w, 0.f);
        f1.x = fmaxf(f1.x, 0.f); f1.y = fmaxf(f1.y, 0.f);
        f1.z = fmaxf(f1.z, 0.f); f1.w = fmaxf(f1.w, 0.f);
    }
    uint4 pk;
    pk.x = packbf(f0.x, f0.y); pk.y = packbf(f0.z, f0.w);
    pk.z = packbf(f1.x, f1.y); pk.w = packbf(f1.z, f1.w);
    ((uint4*)xbf)[i] = pk;
}

// ------------- h = bias + f(x) @ loop_w  (MFMA, consecutive rows, f=relu)
__global__ __launch_bounds__(256) void init_mfma_kernel(const float* __restrict__ xin,
                                                        const u16* __restrict__ lwT,
                                                        const float* __restrict__ bias,
                                                        float* __restrict__ hout,
                                                        int reluIn) {
    __shared__ u16 xlds[8192];    // 16KB: [s][k] swizzled, 64 rows
    int v0 = blockIdx.x * 64;
    int tid = threadIdx.x, lane = tid & 63, w = tid >> 6;

    bf16x8 bfr[2][4];
    #pragma unroll
    for (int n2 = 0; n2 < 2; ++n2) {
        int col = w * 32 + n2 * 16 + (lane & 15);
        #pragma unroll
        for (int ks = 0; ks < 4; ++ks) {
            int k0 = ks * 32 + (lane >> 4) * 8;
            bfr[n2][ks] = *(const bf16x8*)(lwT + (size_t)col * 128 + k0);
        }
    }

    {
        int s = tid >> 2, p = tid & 3;
        int row = v0 + s;
        if (row < N_NODES) {
            const float4* xr = (const float4*)(xin + (size_t)row * 128 + p * 32);
            #pragma unroll
            for (int c = 0; c < 4; ++c) {
                float4 f0 = xr[c * 2], f1 = xr[c * 2 + 1];
                if (reluIn) {
                    f0.x = fmaxf(f0.x, 0.f); f0.y = fmaxf(f0.y, 0.f);
                    f0.z = fmaxf(f0.z, 0.f); f0.w = fmaxf(f0.w, 0.f);
                    f1.x = fmaxf(f1.x, 0.f); f1.y = fmaxf(f1.y, 0.f);
                    f1.z = fmaxf(f1.z, 0.f); f1.w = fmaxf(f1.w, 0.f);
                }
                bf16x8 pk;
                pk[0] = (__bf16)f0.x; pk[1] = (__bf16)f0.y;
                pk[2] = (__bf16)f0.z; pk[3] = (__bf16)f0.w;
                pk[4] = (__bf16)f1.x; pk[5] = (__bf16)f1.y;
                pk[6] = (__bf16)f1.z; pk[7] = (__bf16)f1.w;
                int ch = p * 4 + c;
                *(bf16x8*)((char*)xlds + s * 256 + ((ch * 16) ^ ((s & 7) << 4))) = pk;
            }
        } else {
            bf16x8 z = {(__bf16)0.f, (__bf16)0.f, (__bf16)0.f, (__bf16)0.f,
                        (__bf16)0.f, (__bf16)0.f, (__bf16)0.f, (__bf16)0.f};
            #pragma unroll
            for (int c = 0; c < 4; ++c) {
                int ch = p * 4 + c;
                *(bf16x8*)((char*)xlds + s * 256 + ((ch * 16) ^ ((s & 7) << 4))) = z;
            }
        }
    }
    __syncthreads();

    #pragma unroll
    for (int rt = 0; rt < 4; ++rt) {
        bf16x8 af[4];
        int arow = rt * 16 + (lane & 15);
        #pragma unroll
        for (int ks = 0; ks < 4; ++ks) {
            int k0 = ks * 32 + (lane >> 4) * 8;
            af[ks] = *(const bf16x8*)((const char*)xlds + arow * 256 + ((k0 * 2) ^ ((arow & 7) << 4)));
        }
        f32x4 acc[2];
        acc[0] = (f32x4){0.f, 0.f, 0.f, 0.f};
        acc[1] = (f32x4){0.f, 0.f, 0.f, 0.f};
        #pragma unroll
        for (int ks = 0; ks < 4; ++ks) {
            acc[0] = __builtin_amdgcn_mfma_f32_16x16x32_bf16(bfr[0][ks], af[ks], acc[0], 0, 0, 0);
            acc[1] = __builtin_amdgcn_mfma_f32_16x16x32_bf16(bfr[1][ks], af[ks], acc[1], 0, 0, 0);
        }
        int orow = v0 + rt * 16 + (lane & 15);
        if (orow < N_NODES) {
            #pragma unroll
            for (int n2 = 0; n2 < 2; ++n2) {
                int fbase = w * 32 + n2 * 16 + ((lane >> 4) << 2);
                float4 bv = *(const float4*)(bias + fbase);
                float4 o;
                o.x = acc[n2][0] + bv.x; o.y = acc[n2][1] + bv.y;
                o.z = acc[n2][2] + bv.z; o.w = acc[n2][3] + bv.w;
                *(float4*)(hout + (size_t)orow * 128 + fbase) = o;
            }
        }
    }
}

// ---------------- phase 1: per-edge messages msg[slot] = xbf[src] @ W_r
// block -> tile via XCD swizzle (1800 = 8*225, consecutive tiles = same
// relation land on the same XCD -> W stays in that XCD's L2). Staging is a
// pure 4x uint4 gather copy of the 256B bf16 row into XOR-swizzled LDS.
// SWAPPED mfma(bf, af): lane holds 4 consecutive features of one edge ->
// packed bf16 8B regular stores (L2 write-combines to full lines).
__global__ __launch_bounds__(256) void msg_kernel(const u16* __restrict__ xbf,
                                                  const int* __restrict__ srcPerm,
                                                  const int2* __restrict__ tiles,
                                                  const int* __restrict__ tileCount,
                                                  const u16* __restrict__ WbtT,
                                                  u16* __restrict__ msg) {
    __shared__ u16 xlds[8192];    // 16KB: [s][k] swizzled
    int bid = blockIdx.x;
    int tile = (bid & 7) * (NT_MAX / 8) + (bid >> 3);   // XCD-contiguous
    if (tile >= *tileCount) return;
    int2 td = tiles[tile];
    int slot0 = td.x;
    int r  = td.y >> 9;
    int nE = td.y & 511;
    int tid = threadIdx.x, lane = tid & 63, w = tid >> 6;

    bf16x8 bfr[2][4];
    #pragma unroll
    for (int n2 = 0; n2 < 2; ++n2) {
        int col = w * 32 + n2 * 16 + (lane & 15);
        #pragma unroll
        for (int ks = 0; ks < 4; ++ks) {
            int k0 = ks * 32 + (lane >> 4) * 8;
            bfr[n2][ks] = *(const bf16x8*)(WbtT + (size_t)r * 16384 + col * 128 + k0);
        }
    }

    for (int s0 = 0; s0 < nE; s0 += 64) {
        int cnt = nE - s0; if (cnt > 64) cnt = 64;
        __syncthreads();   // previous subtile's xlds reads complete
        {
            int s = tid >> 2, p = tid & 3;
            if (s < cnt) {
                int xrow = srcPerm[slot0 + s0 + s];
                const uint4* xr = (const uint4*)(xbf + (size_t)xrow * 128);
                #pragma unroll
                for (int c = 0; c < 4; ++c) {
                    int ch = p * 4 + c;
                    *(uint4*)((char*)xlds + s * 256 + ((ch * 16) ^ ((s & 7) << 4))) = xr[ch];
                }
            } else {
                uint4 z = {0u, 0u, 0u, 0u};
                #pragma unroll
                for (int c = 0; c < 4; ++c) {
                    int ch = p * 4 + c;
                    *(uint4*)((char*)xlds + s * 256 + ((ch * 16) ^ ((s & 7) << 4))) = z;
                }
            }
        }
        __syncthreads();

        #pragma unroll
        for (int rt = 0; rt < 4; ++rt) {
            bf16x8 af[4];
            int arow = rt * 16 + (lane & 15);
            #pragma unroll
            for (int ks = 0; ks < 4; ++ks) {
                int k0 = ks * 32 + (lane >> 4) * 8;
                af[ks] = *(const bf16x8*)((const char*)xlds + arow * 256 + ((k0 * 2) ^ ((arow & 7) << 4)));
            }
            f32x4 acc[2];
            acc[0] = (f32x4){0.f, 0.f, 0.f, 0.f};
            acc[1] = (f32x4){0.f, 0.f, 0.f, 0.f};
            #pragma unroll
            for (int ks = 0; ks < 4; ++ks) {
                acc[0] = __builtin_amdgcn_mfma_f32_16x16x32_bf16(bfr[0][ks], af[ks], acc[0], 0, 0, 0);
                acc[1] = __builtin_amdgcn_mfma_f32_16x16x32_bf16(bfr[1][ks], af[ks], acc[1], 0, 0, 0);
            }
            int srow = rt * 16 + (lane & 15);
            if (srow < cnt) {
                int slot = slot0 + s0 + srow;
                #pragma unroll
                for (int n2 = 0; n2 < 2; ++n2) {
                    int fbase = w * 32 + n2 * 16 + ((lane >> 4) << 2);
                    u32x2 pk;
                    pk.x = packbf(acc[n2][0], acc[n2][1]);
                    pk.y = packbf(acc[n2][2], acc[n2][3]);
                    *(u32x2*)(msg + (size_t)slot * 128 + fbase) = pk;
                }
            }
        }
    }
}

// ------------- phase 2: per-node reduce h[v] += sum norm_e * msg_e
__global__ __launch_bounds__(256) void reduce_kernel(const u32* __restrict__ msg32,
                                                     const float* __restrict__ normPerm,
                                                     const int* __restrict__ rowptr,
                                                     const int* __restrict__ dstSlots,
                                                     float* __restrict__ h) {
    int v = blockIdx.x * 4 + (threadIdx.x >> 6);
    int lane = threadIdx.x & 63;
    if (v >= N_NODES) return;
    int p0 = rowptr[v], p1 = rowptr[v + 1];
    float a0 = 0.f, a1 = 0.f, b0 = 0.f, b1 = 0.f;
    int j = p0;
    for (; j + 3 < p1; j += 4) {
        int s0 = dstSlots[j], s1 = dstSlots[j + 1];
        int s2 = dstSlots[j + 2], s3 = dstSlots[j + 3];
        float n0 = normPerm[s0], n1 = normPerm[s1];
        float n2 = normPerm[s2], n3 = normPerm[s3];
        u32 m0 = __builtin_nontemporal_load(msg32 + (size_t)s0 * 64 + lane);
        u32 m1 = __builtin_nontemporal_load(msg32 + (size_t)s1 * 64 + lane);
        u32 m2 = __builtin_nontemporal_load(msg32 + (size_t)s2 * 64 + lane);
        u32 m3 = __builtin_nontemporal_load(msg32 + (size_t)s3 * 64 + lane);
        a0 += n0 * bfbits2f(m0 & 0xffffu); a1 += n0 * bfbits2f(m0 >> 16);
        b0 += n1 * bfbits2f(m1 & 0xffffu); b1 += n1 * bfbits2f(m1 >> 16);
        a0 += n2 * bfbits2f(m2 & 0xffffu); a1 += n2 * bfbits2f(m2 >> 16);
        b0 += n3 * bfbits2f(m3 & 0xffffu); b1 += n3 * bfbits2f(m3 >> 16);
    }
    for (; j < p1; ++j) {
        int s0 = dstSlots[j];
        float n0 = normPerm[s0];
        u32 m0 = __builtin_nontemporal_load(msg32 + (size_t)s0 * 64 + lane);
        a0 += n0 * bfbits2f(m0 & 0xffffu); a1 += n0 * bfbits2f(m0 >> 16);
    }
    float2 hv = *(float2*)(h + (size_t)v * 128 + lane * 2);
    hv.x += a0 + b0;
    hv.y += a1 + b1;
    *(float2*)(h + (size_t)v * 128 + lane * 2) = hv;
}

// ------------------- fallback: fused edge GEMM + fp32 atomic scatter
__global__ __launch_bounds__(256) void edge_atomic_kernel(const float* __restrict__ x,
                                                          const int* __restrict__ src,
                                                          const int* __restrict__ dst,
                                                          const float* __restrict__ norm,
                                                          const int* __restrict__ perm,
                                                          const int2* __restrict__ tiles,
                                                          const int* __restrict__ tileCount,
                                                          const u16* __restrict__ WbtT,
                                                          float* __restrict__ hout,
                                                          int reluIn) {
    __shared__ u16 xlds[8192];
    __shared__ int dlds[64];
    int bid = blockIdx.x;
    if (bid >= *tileCount) return;
    int2 td = tiles[bid];
    int slot0 = td.x;
    int r  = td.y >> 9;
    int nE = td.y & 511;
    int tid = threadIdx.x, lane = tid & 63, w = tid >> 6;

    bf16x8 bfr[2][4];
    #pragma unroll
    for (int n2 = 0; n2 < 2; ++n2) {
        int col = w * 32 + n2 * 16 + (lane & 15);
        #pragma unroll
        for (int ks = 0; ks < 4; ++ks) {
            int k0 = ks * 32 + (lane >> 4) * 8;
            bfr[n2][ks] = *(const bf16x8*)(WbtT + (size_t)r * 16384 + col * 128 + k0);
        }
    }

    for (int s0 = 0; s0 < nE; s0 += 64) {
        int cnt = nE - s0; if (cnt > 64) cnt = 64;
        __syncthreads();
        {
            int s = tid >> 2, p = tid & 3;
            if (s < cnt) {
                int e = perm[slot0 + s0 + s];
                int xrow = src[e];
                float nm = norm[e];
                if (p == 0) dlds[s] = dst[e];
                const float4* xr = (const float4*)(x + (size_t)xrow * 128 + p * 32);
                #pragma unroll
                for (int c = 0; c < 4; ++c) {
                    float4 f0 = xr[c * 2], f1 = xr[c * 2 + 1];
                    if (reluIn) {
                        f0.x = fmaxf(f0.x, 0.f); f0.y = fmaxf(f0.y, 0.f);
                        f0.z = fmaxf(f0.z, 0.f); f0.w = fmaxf(f0.w, 0.f);
                        f1.x = fmaxf(f1.x, 0.f); f1.y = fmaxf(f1.y, 0.f);
                        f1.z = fmaxf(f1.z, 0.f); f1.w = fmaxf(f1.w, 0.f);
                    }
                    bf16x8 pk;
                    pk[0] = (__bf16)(f0.x * nm); pk[1] = (__bf16)(f0.y * nm);
                    pk[2] = (__bf16)(f0.z * nm); pk[3] = (__bf16)(f0.w * nm);
                    pk[4] = (__bf16)(f1.x * nm); pk[5] = (__bf16)(f1.y * nm);
                    pk[6] = (__bf16)(f1.z * nm); pk[7] = (__bf16)(f1.w * nm);
                    int ch = p * 4 + c;
                    *(bf16x8*)((char*)xlds + s * 256 + ((ch * 16) ^ ((s & 7) << 4))) = pk;
                }
            } else {
                bf16x8 z = {(__bf16)0.f, (__bf16)0.f, (__bf16)0.f, (__bf16)0.f,
                            (__bf16)0.f, (__bf16)0.f, (__bf16)0.f, (__bf16)0.f};
                #pragma unroll
                for (int c = 0; c < 4; ++c) {
                    int ch = p * 4 + c;
                    *(bf16x8*)((char*)xlds + s * 256 + ((ch * 16) ^ ((s & 7) << 4))) = z;
                }
            }
        }
        __syncthreads();

        #pragma unroll
        for (int rt = 0; rt < 4; ++rt) {
            bf16x8 af[4];
            int arow = rt * 16 + (lane & 15);
            #pragma unroll
            for (int ks = 0; ks < 4; ++ks) {
                int k0 = ks * 32 + (lane >> 4) * 8;
                af[ks] = *(const bf16x8*)((const char*)xlds + arow * 256 + ((k0 * 2) ^ ((arow & 7) << 4)));
            }
            f32x4 acc[2];
            acc[0] = (f32x4){0.f, 0.f, 0.f, 0.f};
            acc[1] = (f32x4){0.f, 0.f, 0.f, 0.f};
            #pragma unroll
            for (int ks = 0; ks < 4; ++ks) {
                acc[0] = __builtin_amdgcn_mfma_f32_16x16x32_bf16(bfr[0][ks], af[ks], acc[0], 0, 0, 0);
                acc[1] = __builtin_amdgcn_mfma_f32_16x16x32_bf16(bfr[1][ks], af[ks], acc[1], 0, 0, 0);
            }
            int srow = rt * 16 + (lane & 15);
            if (srow < cnt) {
                int d = dlds[srow];
                #pragma unroll
                for (int n2 = 0; n2 < 2; ++n2) {
                    float* hp = hout + (size_t)d * 128 + w * 32 + n2 * 16 + ((lane >> 4) << 2);
                    #pragma unroll
                    for (int reg = 0; reg < 4; ++reg) atomicAdd(hp + reg, acc[n2][reg]);
                }
            }
        }
    }
}

// ------------------------------------------------------------------ launch
extern "C" void kernel_launch(void* const* d_in, const int* in_sizes, int n_in,
                              void* d_out, int out_size, void* d_ws, size_t ws_size,
                              hipStream_t stream) {
    const int*   src   = (const int*)  d_in[1];
    const int*   dst   = (const int*)  d_in[2];
    const int*   etype = (const int*)  d_in[3];
    const float* norm  = (const float*)d_in[4];
    const float* emb   = (const float*)d_in[6];
    const float* V1    = (const float*)d_in[7];
    const float* comp1 = (const float*)d_in[8];
    const float* loop1 = (const float*)d_in[9];
    const float* bias1 = (const float*)d_in[10];
    const float* V2    = (const float*)d_in[11];
    const float* comp2 = (const float*)d_in[12];
    const float* loop2 = (const float*)d_in[13];
    const float* bias2 = (const float*)d_in[14];
    float* out = (float*)d_out;

    char* ws = (char*)d_ws;
    size_t off = 0;
    auto carve = [&](size_t bytes) -> void* {
        void* p = ws + off;
        off += (bytes + 255) & ~(size_t)255;
        return p;
    };
    const size_t WB = (size_t)N_RELS * 16384 * 2;                 // 7.77 MB
    u16* Wbt1      = (u16*)carve(WB);
    u16* Wbt2      = (u16*)carve(WB);
    void* uni      = carve(WB);                                   // union: rm / h1
    u16*   rm      = (u16*)uni;
    float* h1      = (float*)uni;
    int*  perm     = (int*)carve((size_t)N_EDGES * 4);
    int*  srcPerm  = (int*)carve((size_t)N_EDGES * 4);
    float* normPerm= (float*)carve((size_t)N_EDGES * 4);
    int*  blockHist= (int*)carve((size_t)N_RELS * NB_SORT * 4);
    int*  baseOff  = (int*)carve((size_t)N_RELS * NB_SORT * 4);
    int2* tiles    = (int2*)carve((size_t)NT_MAX * 8);
    int*  tileCnt  = (int*)carve(256);
    u16*  lwT1     = (u16*)carve(128 * 128 * 2);
    u16*  lwT2     = (u16*)carve(128 * 128 * 2);
    int*  deg      = (int*)carve((size_t)N_NODES * 4);
    int*  rowptr   = (int*)carve((size_t)(N_NODES + 1) * 4);
    int*  cursor   = (int*)carve((size_t)(N_NODES + 1) * 4);
    int*  dstSlots = (int*)carve((size_t)N_EDGES * 4);
    u16*  xbf      = (u16*)carve((size_t)N_NODES * 128 * 2);      // 3.84 MB
    u16*  msg      = (u16*)carve((size_t)N_EDGES * 128 * 2);      // 102.4 MB
    bool twoPhase = (off <= ws_size);                             // call-invariant

    // ---- sort edges by relation (shared by both layers), contention-free
    histA_kernel<<<NB_SORT, 256, 0, stream>>>(etype, blockHist);
    scanB_kernel<<<1, 256, 0, stream>>>(blockHist, baseOff, tiles, tileCnt);
    scatterC_kernel<<<NB_SORT, 256, 0, stream>>>(etype, src, norm, baseOff,
                                                 perm, srcPerm, normPerm);

    if (twoPhase) {
        // ---- dst-CSR (slot lists per destination node)
        zeroDeg_kernel<<<59, 256, 0, stream>>>(deg);
        degcnt_kernel<<<391, 256, 0, stream>>>(dst, deg);
        scanDeg_kernel<<<1, 256, 0, stream>>>(deg, rowptr, cursor);
        scatterDst_kernel<<<391, 256, 0, stream>>>(dst, perm, cursor, dstSlots);
    }

    // ---- per-relation weights (bf16, linear col-major W^T image)
    dim3 wg(8, 64);
    wgemm_kernel<<<wg, 256, 0, stream>>>(comp1, V1, rm);
    transp_kernel<<<N_RELS, 256, 0, stream>>>(rm, Wbt1);
    wgemm_kernel<<<wg, 256, 0, stream>>>(comp2, V2, rm);
    transp_kernel<<<N_RELS, 256, 0, stream>>>(rm, Wbt2);
    loopT_kernel<<<1, 256, 0, stream>>>(loop1, lwT1);
    loopT_kernel<<<1, 256, 0, stream>>>(loop2, lwT2);

    if (twoPhase) {
        // ---- layer 1
        xbf_kernel<<<938, 256, 0, stream>>>(emb, xbf, 0);
        init_mfma_kernel<<<235, 256, 0, stream>>>(emb, lwT1, bias1, h1, 0);
        msg_kernel<<<NT_MAX, 256, 0, stream>>>(xbf, srcPerm, tiles, tileCnt,
                                               Wbt1, msg);
        reduce_kernel<<<3750, 256, 0, stream>>>((const u32*)msg, normPerm,
                                                rowptr, dstSlots, h1);
        // ---- layer 2
        xbf_kernel<<<938, 256, 0, stream>>>(h1, xbf, 1);
        init_mfma_kernel<<<235, 256, 0, stream>>>(h1, lwT2, bias2, out, 1);
        msg_kernel<<<NT_MAX, 256, 0, stream>>>(xbf, srcPerm, tiles, tileCnt,
                                               Wbt2, msg);
        reduce_kernel<<<3750, 256, 0, stream>>>((const u32*)msg, normPerm,
                                                rowptr, dstSlots, out);
    } else {
        // ---- fallback: fused atomic scatter (small workspace)
        init_mfma_kernel<<<235, 256, 0, stream>>>(emb, lwT1, bias1, h1, 0);
        edge_atomic_kernel<<<NT_MAX, 256, 0, stream>>>(emb, src, dst, norm, perm, tiles,
                                                       tileCnt, Wbt1, h1, 0);
        init_mfma_kernel<<<235, 256, 0, stream>>>(h1, lwT2, bias2, out, 1);
        edge_atomic_kernel<<<NT_MAX, 256, 0, stream>>>(h1, src, dst, norm, perm, tiles,
                                                       tileCnt, Wbt2, out, 1);
    }
}

// Round 9
// 413.475 us; speedup vs baseline: 1.5748x; 1.1755x over previous
//
#include <hip/hip_runtime.h>
#include <hip/hip_bf16.h>

// RGCN 2-layer forward, MI355X.
// Two-phase edge flow: msg_kernel writes unscaled bf16 message rows x@W_r
// (regular stores, no atomics); reduce_kernel sums norm_e * msg_e per dst
// node via a dst-CSR (one wave per node, 4-deep ILP). x pre-cast to bf16
// (relu folded) so the gather is 256B/row. Per-relation W^T image built by
// one bf16 MFMA GEMM (comp @ V^T-image) -- no separate transpose pass.
// Edges counting-sorted by etype; XCD-aware tile swizzle for W L2 locality.
// Fallback atomic path if d_ws is too small for the 102 MB message buffer.

typedef unsigned short u16;
typedef unsigned int   u32;
typedef __bf16 bf16x8 __attribute__((ext_vector_type(8)));
typedef float  f32x4  __attribute__((ext_vector_type(4)));
typedef u32    u32x2  __attribute__((ext_vector_type(2)));

#define N_NODES 15000
#define N_EDGES 400000
#define N_RELS  237
#define N_BASES 100
#define NT_MAX  1800   // 8 * 225, >= sum ceil(n_r/256) (max 1799)
#define NB_SORT 196    // sort chunks
#define CHUNK   2048   // NB_SORT*CHUNK = 401408 >= N_EDGES

__device__ __forceinline__ u32 packbf(float a, float b) {
    u16 lo = __builtin_bit_cast(u16, (__bf16)a);
    u16 hi = __builtin_bit_cast(u16, (__bf16)b);
    return (u32)lo | ((u32)hi << 16);
}
__device__ __forceinline__ u16 bf16bits(float a) {
    return __builtin_bit_cast(u16, (__bf16)a);
}
__device__ __forceinline__ float bfbits2f(u32 hi16) {   // hi16 in low 16 bits
    u32 x = hi16 << 16;
    return __builtin_bit_cast(float, x);
}

// -------------------------------------------------- pass A: block histogram
__global__ __launch_bounds__(256) void histA_kernel(const int* __restrict__ etype,
                                                    int* __restrict__ blockHist) {
    __shared__ int hh[256];
    int tid = threadIdx.x, b = blockIdx.x;
    hh[tid] = 0;
    __syncthreads();
    int e0 = b * CHUNK;
    int e1 = e0 + CHUNK; if (e1 > N_EDGES) e1 = N_EDGES;
    for (int e = e0 + tid; e < e1; e += 256)
        atomicAdd(&hh[etype[e]], 1);
    __syncthreads();
    if (tid < N_RELS) blockHist[tid * NB_SORT + b] = hh[tid];
}

// ------------------- pass B: totals, prefix, tiles, per-block base offsets
__global__ __launch_bounds__(256) void scanB_kernel(const int* __restrict__ blockHist,
                                                    int* __restrict__ baseOff,
                                                    int2* __restrict__ tiles,
                                                    int* __restrict__ tileCount) {
    __shared__ int h[256], o[256], to[256];
    int tid = threadIdx.x;
    int sum = 0;
    if (tid < N_RELS)
        for (int b = 0; b < NB_SORT; ++b) sum += blockHist[tid * NB_SORT + b];
    h[tid] = (tid < N_RELS) ? sum : 0;
    __syncthreads();
    if (tid == 0) {
        int run = 0, tc = 0;
        for (int r = 0; r < N_RELS; ++r) {
            o[r] = run; run += h[r];
            to[r] = tc; tc += (h[r] + 255) >> 8;
        }
        *tileCount = tc;
    }
    __syncthreads();
    if (tid < N_RELS) {
        int n = h[tid], t0 = to[tid], base = o[tid];
        for (int t = 0; t * 256 < n; ++t) {
            int nE = n - t * 256; if (nE > 256) nE = 256;
            tiles[t0 + t] = make_int2(base + t * 256, (tid << 9) | nE);
        }
        int run = base;
        for (int b = 0; b < NB_SORT; ++b) {
            baseOff[tid * NB_SORT + b] = run;
            run += blockHist[tid * NB_SORT + b];
        }
    }
}

// ----------- pass C: scatter with LDS cursors; also emit srcPerm/normPerm
__global__ __launch_bounds__(256) void scatterC_kernel(const int* __restrict__ etype,
                                                       const int* __restrict__ src,
                                                       const float* __restrict__ norm,
                                                       const int* __restrict__ baseOff,
                                                       int* __restrict__ perm,
                                                       int* __restrict__ srcPerm,
                                                       float* __restrict__ normPerm) {
    __shared__ int lcur[256];
    int tid = threadIdx.x, b = blockIdx.x;
    if (tid < N_RELS) lcur[tid] = baseOff[tid * NB_SORT + b];
    __syncthreads();
    int e0 = b * CHUNK;
    int e1 = e0 + CHUNK; if (e1 > N_EDGES) e1 = N_EDGES;
    for (int e = e0 + tid; e < e1; e += 256) {
        int r = etype[e];
        int pos = atomicAdd(&lcur[r], 1);
        perm[pos] = e;
        srcPerm[pos] = src[e];
        normPerm[pos] = norm[e];
    }
}

// ----------------------------------------- dst-CSR build (for reduce pass)
__global__ __launch_bounds__(256) void zeroDeg_kernel(int* __restrict__ deg) {
    int i = blockIdx.x * 256 + threadIdx.x;
    if (i < N_NODES) deg[i] = 0;
}
__global__ __launch_bounds__(256) void degcnt_kernel(const int* __restrict__ dst,
                                                     int* __restrict__ deg) {
    for (int e = blockIdx.x * 256 + threadIdx.x; e < N_EDGES; e += gridDim.x * 256)
        atomicAdd(&deg[dst[e]], 1);
}
__global__ __launch_bounds__(256) void scanDeg_kernel(const int* __restrict__ deg,
                                                      int* __restrict__ rowptr,
                                                      int* __restrict__ cursor) {
    __shared__ int part[256];
    int tid = threadIdx.x;
    const int R = 59;                       // 256*59 = 15104 >= 15001
    int lo = tid * R, hi = lo + R; if (hi > N_NODES + 1) hi = N_NODES + 1;
    int s = 0;
    for (int i = lo; i < hi; ++i) s += (i < N_NODES) ? deg[i] : 0;
    part[tid] = s;
    __syncthreads();
    if (tid == 0) {
        int run = 0;
        for (int t = 0; t < 256; ++t) { int tmp = part[t]; part[t] = run; run += tmp; }
    }
    __syncthreads();
    int run = part[tid];
    for (int i = lo; i < hi; ++i) {
        rowptr[i] = run; cursor[i] = run;
        run += (i < N_NODES) ? deg[i] : 0;
    }
}
__global__ __launch_bounds__(256) void scatterDst_kernel(const int* __restrict__ dst,
                                                         const int* __restrict__ perm,
                                                         int* __restrict__ cursor,
                                                         int* __restrict__ dstSlots) {
    for (int s = blockIdx.x * 256 + threadIdx.x; s < N_EDGES; s += gridDim.x * 256) {
        int e = perm[s];
        int v = dst[e];
        int pos = atomicAdd(&cursor[v], 1);   // ~27 edges/node: low contention
        dstSlots[pos] = s;
    }
}

// ------------------------- comp (fp32 [237][100]) -> bf16 [256][128] padded
__global__ __launch_bounds__(256) void compcast_kernel(const float* __restrict__ comp,
                                                       u16* __restrict__ compbf) {
    int idx = blockIdx.x * 256 + threadIdx.x;    // 32768 total
    if (idx >= 256 * 128) return;
    int r = idx >> 7, b = idx & 127;
    float v = (r < N_RELS && b < N_BASES) ? comp[(size_t)r * N_BASES + b] : 0.f;
    compbf[idx] = bf16bits(v);
}

// ------ V (fp32 [100][128][128]) -> aimg bf16: aimg[(col*128+k)*128 + b]
// = V[b][k][col]; rows b>=100 zeroed. One block per k; LDS transpose.
__global__ __launch_bounds__(256) void vt_kernel(const float* __restrict__ V,
                                                 u16* __restrict__ aimg) {
    __shared__ u16 t[128 * 130];      // [col][b] padded
    int k = blockIdx.x, tid = threadIdx.x;
    #pragma unroll
    for (int i = 0; i < 64; ++i) {
        int idx = i * 256 + tid;      // b = idx>>7, col = idx&127
        int b = idx >> 7, col = idx & 127;
        float v = (b < N_BASES) ? V[(size_t)b * 16384 + k * 128 + col] : 0.f;
        t[col * 130 + b] = bf16bits(v);
    }
    __syncthreads();
    #pragma unroll
    for (int i = 0; i < 64; ++i) {
        int idx = i * 256 + tid;      // col = idx>>7, b = idx&127
        int col = idx >> 7, b = idx & 127;
        aimg[((size_t)col * 128 + k) * 128 + b] = t[col * 130 + b];
    }
}

// ---------- Wbt[r][j] = sum_b comp[r][b] * aimg[j][b]   (MFMA, j=col*128+k)
// block: 64 relations x 128 j; A-op = aimg frags (global), B-op = comp rows
// staged in swizzled LDS; lane holds 4 consecutive j of one r -> 8B stores.
__global__ __launch_bounds__(256) void wgemmT_kernel(const u16* __restrict__ compbf,
                                                     const u16* __restrict__ aimg,
                                                     u16* __restrict__ Wbt) {
    __shared__ u16 clds[8192];        // 64 rows x 128 k swizzled
    int m0 = blockIdx.x * 64, n0 = blockIdx.y * 128;
    int tid = threadIdx.x, lane = tid & 63, w = tid >> 6;

    bf16x8 afr[2][4];
    #pragma unroll
    for (int n2 = 0; n2 < 2; ++n2) {
        int j = n0 + w * 32 + n2 * 16 + (lane & 15);
        #pragma unroll
        for (int ks = 0; ks < 4; ++ks) {
            int b0 = ks * 32 + (lane >> 4) * 8;
            afr[n2][ks] = *(const bf16x8*)(aimg + (size_t)j * 128 + b0);
        }
    }
    {
        int s = tid >> 2, p = tid & 3;
        const uint4* cr = (const uint4*)(compbf + (size_t)(m0 + s) * 128);
        #pragma unroll
        for (int c = 0; c < 4; ++c) {
            int ch = p * 4 + c;
            *(uint4*)((char*)clds + s * 256 + ((ch * 16) ^ ((s & 7) << 4))) = cr[ch];
        }
    }
    __syncthreads();

    #pragma unroll
    for (int rt = 0; rt < 4; ++rt) {
        bf16x8 cf[4];
        int arow = rt * 16 + (lane & 15);
        #pragma unroll
        for (int ks = 0; ks < 4; ++ks) {
            int k0 = ks * 32 + (lane >> 4) * 8;
            cf[ks] = *(const bf16x8*)((const char*)clds + arow * 256 + ((k0 * 2) ^ ((arow & 7) << 4)));
        }
        f32x4 acc[2];
        acc[0] = (f32x4){0.f, 0.f, 0.f, 0.f};
        acc[1] = (f32x4){0.f, 0.f, 0.f, 0.f};
        #pragma unroll
        for (int ks = 0; ks < 4; ++ks) {
            acc[0] = __builtin_amdgcn_mfma_f32_16x16x32_bf16(afr[0][ks], cf[ks], acc[0], 0, 0, 0);
            acc[1] = __builtin_amdgcn_mfma_f32_16x16x32_bf16(afr[1][ks], cf[ks], acc[1], 0, 0, 0);
        }
        int r = m0 + rt * 16 + (lane & 15);
        if (r < N_RELS) {
            #pragma unroll
            for (int n2 = 0; n2 < 2; ++n2) {
                int jb = n0 + w * 32 + n2 * 16 + ((lane >> 4) << 2);
                u32x2 pk;
                pk.x = packbf(acc[n2][0], acc[n2][1]);
                pk.y = packbf(acc[n2][2], acc[n2][3]);
                *(u32x2*)(Wbt + (size_t)r * 16384 + jb) = pk;
            }
        }
    }
}

// ---------- loop_w (fp32 RM [k][n]) -> bf16 col-major W^T image (linear)
__global__ __launch_bounds__(256) void loopT_kernel(const float* __restrict__ lw,
                                                    u16* __restrict__ outT) {
    int tid = threadIdx.x;
    u32* outu = (u32*)outT;
    #pragma unroll
    for (int i = 0; i < 32; ++i) {
        int idx = i * 256 + tid;           // col = idx>>6, kk2 = idx&63
        int col = idx >> 6, kk2 = idx & 63;
        float a = lw[(size_t)(2 * kk2) * 128 + col];
        float b = lw[(size_t)(2 * kk2 + 1) * 128 + col];
        outu[col * 64 + kk2] = packbf(a, b);
    }
}

// ------------------- x (fp32, optional relu) -> bf16 row image [v][128]
__global__ __launch_bounds__(256) void xbf_kernel(const float* __restrict__ x,
                                                  u16* __restrict__ xbf,
                                                  int reluIn) {
    int i = blockIdx.x * 256 + threadIdx.x;     // one thread = 8 features
    if (i >= N_NODES * 16) return;
    const float4* xp = (const float4*)x;
    float4 f0 = xp[i * 2], f1 = xp[i * 2 + 1];
    if (reluIn) {
        f0.x = fmaxf(f0.x, 0.f); f0.y = fmaxf(f0.y, 0.f);
        f0.z = fmaxf(f0.z, 0.f); f0.w = fmaxf(f0.w, 0.f);
        f1.x = fmaxf(f1.x, 0.f); f1.y = fmaxf(f1.y, 0.f);
        f1.z = fmaxf(f1.z, 0.f); f1.w = fmaxf(f1.w, 0.f);
    }
    uint4 pk;
    pk.x = packbf(f0.x, f0.y); pk.y = packbf(f0.z, f0.w);
    pk.z = packbf(f1.x, f1.y); pk.w = packbf(f1.z, f1.w);
    ((uint4*)xbf)[i] = pk;
}

// ------------- h = bias + f(x) @ loop_w  (MFMA, consecutive rows, f=relu)
__global__ __launch_bounds__(256) void init_mfma_kernel(const float* __restrict__ xin,
                                                        const u16* __restrict__ lwT,
                                                        const float* __restrict__ bias,
                                                        float* __restrict__ hout,
                                                        int reluIn) {
    __shared__ u16 xlds[8192];    // 16KB: [s][k] swizzled, 64 rows
    int v0 = blockIdx.x * 64;
    int tid = threadIdx.x, lane = tid & 63, w = tid >> 6;

    bf16x8 bfr[2][4];
    #pragma unroll
    for (int n2 = 0; n2 < 2; ++n2) {
        int col = w * 32 + n2 * 16 + (lane & 15);
        #pragma unroll
        for (int ks = 0; ks < 4; ++ks) {
            int k0 = ks * 32 + (lane >> 4) * 8;
            bfr[n2][ks] = *(const bf16x8*)(lwT + (size_t)col * 128 + k0);
        }
    }

    {
        int s = tid >> 2, p = tid & 3;
        int row = v0 + s;
        if (row < N_NODES) {
            const float4* xr = (const float4*)(xin + (size_t)row * 128 + p * 32);
            #pragma unroll
            for (int c = 0; c < 4; ++c) {
                float4 f0 = xr[c * 2], f1 = xr[c * 2 + 1];
                if (reluIn) {
                    f0.x = fmaxf(f0.x, 0.f); f0.y = fmaxf(f0.y, 0.f);
                    f0.z = fmaxf(f0.z, 0.f); f0.w = fmaxf(f0.w, 0.f);
                    f1.x = fmaxf(f1.x, 0.f); f1.y = fmaxf(f1.y, 0.f);
                    f1.z = fmaxf(f1.z, 0.f); f1.w = fmaxf(f1.w, 0.f);
                }
                bf16x8 pk;
                pk[0] = (__bf16)f0.x; pk[1] = (__bf16)f0.y;
                pk[2] = (__bf16)f0.z; pk[3] = (__bf16)f0.w;
                pk[4] = (__bf16)f1.x; pk[5] = (__bf16)f1.y;
                pk[6] = (__bf16)f1.z; pk[7] = (__bf16)f1.w;
                int ch = p * 4 + c;
                *(bf16x8*)((char*)xlds + s * 256 + ((ch * 16) ^ ((s & 7) << 4))) = pk;
            }
        } else {
            bf16x8 z = {(__bf16)0.f, (__bf16)0.f, (__bf16)0.f, (__bf16)0.f,
                        (__bf16)0.f, (__bf16)0.f, (__bf16)0.f, (__bf16)0.f};
            #pragma unroll
            for (int c = 0; c < 4; ++c) {
                int ch = p * 4 + c;
                *(bf16x8*)((char*)xlds + s * 256 + ((ch * 16) ^ ((s & 7) << 4))) = z;
            }
        }
    }
    __syncthreads();

    #pragma unroll
    for (int rt = 0; rt < 4; ++rt) {
        bf16x8 af[4];
        int arow = rt * 16 + (lane & 15);
        #pragma unroll
        for (int ks = 0; ks < 4; ++ks) {
            int k0 = ks * 32 + (lane >> 4) * 8;
            af[ks] = *(const bf16x8*)((const char*)xlds + arow * 256 + ((k0 * 2) ^ ((arow & 7) << 4)));
        }
        f32x4 acc[2];
        acc[0] = (f32x4){0.f, 0.f, 0.f, 0.f};
        acc[1] = (f32x4){0.f, 0.f, 0.f, 0.f};
        #pragma unroll
        for (int ks = 0; ks < 4; ++ks) {
            acc[0] = __builtin_amdgcn_mfma_f32_16x16x32_bf16(bfr[0][ks], af[ks], acc[0], 0, 0, 0);
            acc[1] = __builtin_amdgcn_mfma_f32_16x16x32_bf16(bfr[1][ks], af[ks], acc[1], 0, 0, 0);
        }
        int orow = v0 + rt * 16 + (lane & 15);
        if (orow < N_NODES) {
            #pragma unroll
            for (int n2 = 0; n2 < 2; ++n2) {
                int fbase = w * 32 + n2 * 16 + ((lane >> 4) << 2);
                float4 bv = *(const float4*)(bias + fbase);
                float4 o;
                o.x = acc[n2][0] + bv.x; o.y = acc[n2][1] + bv.y;
                o.z = acc[n2][2] + bv.z; o.w = acc[n2][3] + bv.w;
                *(float4*)(hout + (size_t)orow * 128 + fbase) = o;
            }
        }
    }
}

// ---------------- phase 1: per-edge messages msg[slot] = xbf[src] @ W_r
// block -> tile via XCD swizzle (1800 = 8*225); staging is a pure 4x uint4
// gather of the 256B bf16 row into XOR-swizzled LDS. SWAPPED mfma(bf, af):
// lane holds 4 consecutive features of one edge -> 8B regular stores.
__global__ __launch_bounds__(256) void msg_kernel(const u16* __restrict__ xbf,
                                                  const int* __restrict__ srcPerm,
                                                  const int2* __restrict__ tiles,
                                                  const int* __restrict__ tileCount,
                                                  const u16* __restrict__ WbtT,
                                                  u16* __restrict__ msg) {
    __shared__ u16 xlds[8192];    // 16KB: [s][k] swizzled
    int bid = blockIdx.x;
    int tile = (bid & 7) * (NT_MAX / 8) + (bid >> 3);   // XCD-contiguous
    if (tile >= *tileCount) return;
    int2 td = tiles[tile];
    int slot0 = td.x;
    int r  = td.y >> 9;
    int nE = td.y & 511;
    int tid = threadIdx.x, lane = tid & 63, w = tid >> 6;

    bf16x8 bfr[2][4];
    #pragma unroll
    for (int n2 = 0; n2 < 2; ++n2) {
        int col = w * 32 + n2 * 16 + (lane & 15);
        #pragma unroll
        for (int ks = 0; ks < 4; ++ks) {
            int k0 = ks * 32 + (lane >> 4) * 8;
            bfr[n2][ks] = *(const bf16x8*)(WbtT + (size_t)r * 16384 + col * 128 + k0);
        }
    }

    for (int s0 = 0; s0 < nE; s0 += 64) {
        int cnt = nE - s0; if (cnt > 64) cnt = 64;
        __syncthreads();   // previous subtile's xlds reads complete
        {
            int s = tid >> 2, p = tid & 3;
            if (s < cnt) {
                int xrow = srcPerm[slot0 + s0 + s];
                const uint4* xr = (const uint4*)(xbf + (size_t)xrow * 128);
                #pragma unroll
                for (int c = 0; c < 4; ++c) {
                    int ch = p * 4 + c;
                    *(uint4*)((char*)xlds + s * 256 + ((ch * 16) ^ ((s & 7) << 4))) = xr[ch];
                }
            } else {
                uint4 z = {0u, 0u, 0u, 0u};
                #pragma unroll
                for (int c = 0; c < 4; ++c) {
                    int ch = p * 4 + c;
                    *(uint4*)((char*)xlds + s * 256 + ((ch * 16) ^ ((s & 7) << 4))) = z;
                }
            }
        }
        __syncthreads();

        #pragma unroll
        for (int rt = 0; rt < 4; ++rt) {
            bf16x8 af[4];
            int arow = rt * 16 + (lane & 15);
            #pragma unroll
            for (int ks = 0; ks < 4; ++ks) {
                int k0 = ks * 32 + (lane >> 4) * 8;
                af[ks] = *(const bf16x8*)((const char*)xlds + arow * 256 + ((k0 * 2) ^ ((arow & 7) << 4)));
            }
            f32x4 acc[2];
            acc[0] = (f32x4){0.f, 0.f, 0.f, 0.f};
            acc[1] = (f32x4){0.f, 0.f, 0.f, 0.f};
            #pragma unroll
            for (int ks = 0; ks < 4; ++ks) {
                acc[0] = __builtin_amdgcn_mfma_f32_16x16x32_bf16(bfr[0][ks], af[ks], acc[0], 0, 0, 0);
                acc[1] = __builtin_amdgcn_mfma_f32_16x16x32_bf16(bfr[1][ks], af[ks], acc[1], 0, 0, 0);
            }
            int srow = rt * 16 + (lane & 15);
            if (srow < cnt) {
                int slot = slot0 + s0 + srow;
                #pragma unroll
                for (int n2 = 0; n2 < 2; ++n2) {
                    int fbase = w * 32 + n2 * 16 + ((lane >> 4) << 2);
                    u32x2 pk;
                    pk.x = packbf(acc[n2][0], acc[n2][1]);
                    pk.y = packbf(acc[n2][2], acc[n2][3]);
                    *(u32x2*)(msg + (size_t)slot * 128 + fbase) = pk;
                }
            }
        }
    }
}

// ------------- phase 2: per-node reduce h[v] += sum norm_e * msg_e
__global__ __launch_bounds__(256) void reduce_kernel(const u32* __restrict__ msg32,
                                                     const float* __restrict__ normPerm,
                                                     const int* __restrict__ rowptr,
                                                     const int* __restrict__ dstSlots,
                                                     float* __restrict__ h) {
    int v = blockIdx.x * 4 + (threadIdx.x >> 6);
    int lane = threadIdx.x & 63;
    if (v >= N_NODES) return;
    int p0 = rowptr[v], p1 = rowptr[v + 1];
    float a0 = 0.f, a1 = 0.f, b0 = 0.f, b1 = 0.f;
    int j = p0;
    for (; j + 3 < p1; j += 4) {
        int s0 = dstSlots[j], s1 = dstSlots[j + 1];
        int s2 = dstSlots[j + 2], s3 = dstSlots[j + 3];
        float n0 = normPerm[s0], n1 = normPerm[s1];
        float n2 = normPerm[s2], n3 = normPerm[s3];
        u32 m0 = __builtin_nontemporal_load(msg32 + (size_t)s0 * 64 + lane);
        u32 m1 = __builtin_nontemporal_load(msg32 + (size_t)s1 * 64 + lane);
        u32 m2 = __builtin_nontemporal_load(msg32 + (size_t)s2 * 64 + lane);
        u32 m3 = __builtin_nontemporal_load(msg32 + (size_t)s3 * 64 + lane);
        a0 += n0 * bfbits2f(m0 & 0xffffu); a1 += n0 * bfbits2f(m0 >> 16);
        b0 += n1 * bfbits2f(m1 & 0xffffu); b1 += n1 * bfbits2f(m1 >> 16);
        a0 += n2 * bfbits2f(m2 & 0xffffu); a1 += n2 * bfbits2f(m2 >> 16);
        b0 += n3 * bfbits2f(m3 & 0xffffu); b1 += n3 * bfbits2f(m3 >> 16);
    }
    for (; j < p1; ++j) {
        int s0 = dstSlots[j];
        float n0 = normPerm[s0];
        u32 m0 = __builtin_nontemporal_load(msg32 + (size_t)s0 * 64 + lane);
        a0 += n0 * bfbits2f(m0 & 0xffffu); a1 += n0 * bfbits2f(m0 >> 16);
    }
    float2 hv = *(float2*)(h + (size_t)v * 128 + lane * 2);
    hv.x += a0 + b0;
    hv.y += a1 + b1;
    *(float2*)(h + (size_t)v * 128 + lane * 2) = hv;
}

// ------------------- fallback: fused edge GEMM + fp32 atomic scatter
__global__ __launch_bounds__(256) void edge_atomic_kernel(const float* __restrict__ x,
                                                          const int* __restrict__ src,
                                                          const int* __restrict__ dst,
                                                          const float* __restrict__ norm,
                                                          const int* __restrict__ perm,
                                                          const int2* __restrict__ tiles,
                                                          const int* __restrict__ tileCount,
                                                          const u16* __restrict__ WbtT,
                                                          float* __restrict__ hout,
                                                          int reluIn) {
    __shared__ u16 xlds[8192];
    __shared__ int dlds[64];
    int bid = blockIdx.x;
    if (bid >= *tileCount) return;
    int2 td = tiles[bid];
    int slot0 = td.x;
    int r  = td.y >> 9;
    int nE = td.y & 511;
    int tid = threadIdx.x, lane = tid & 63, w = tid >> 6;

    bf16x8 bfr[2][4];
    #pragma unroll
    for (int n2 = 0; n2 < 2; ++n2) {
        int col = w * 32 + n2 * 16 + (lane & 15);
        #pragma unroll
        for (int ks = 0; ks < 4; ++ks) {
            int k0 = ks * 32 + (lane >> 4) * 8;
            bfr[n2][ks] = *(const bf16x8*)(WbtT + (size_t)r * 16384 + col * 128 + k0);
        }
    }

    for (int s0 = 0; s0 < nE; s0 += 64) {
        int cnt = nE - s0; if (cnt > 64) cnt = 64;
        __syncthreads();
        {
            int s = tid >> 2, p = tid & 3;
            if (s < cnt) {
                int e = perm[slot0 + s0 + s];
                int xrow = src[e];
                float nm = norm[e];
                if (p == 0) dlds[s] = dst[e];
                const float4* xr = (const float4*)(x + (size_t)xrow * 128 + p * 32);
                #pragma unroll
                for (int c = 0; c < 4; ++c) {
                    float4 f0 = xr[c * 2], f1 = xr[c * 2 + 1];
                    if (reluIn) {
                        f0.x = fmaxf(f0.x, 0.f); f0.y = fmaxf(f0.y, 0.f);
                        f0.z = fmaxf(f0.z, 0.f); f0.w = fmaxf(f0.w, 0.f);
                        f1.x = fmaxf(f1.x, 0.f); f1.y = fmaxf(f1.y, 0.f);
                        f1.z = fmaxf(f1.z, 0.f); f1.w = fmaxf(f1.w, 0.f);
                    }
                    bf16x8 pk;
                    pk[0] = (__bf16)(f0.x * nm); pk[1] = (__bf16)(f0.y * nm);
                    pk[2] = (__bf16)(f0.z * nm); pk[3] = (__bf16)(f0.w * nm);
                    pk[4] = (__bf16)(f1.x * nm); pk[5] = (__bf16)(f1.y * nm);
                    pk[6] = (__bf16)(f1.z * nm); pk[7] = (__bf16)(f1.w * nm);
                    int ch = p * 4 + c;
                    *(bf16x8*)((char*)xlds + s * 256 + ((ch * 16) ^ ((s & 7) << 4))) = pk;
                }
            } else {
                bf16x8 z = {(__bf16)0.f, (__bf16)0.f, (__bf16)0.f, (__bf16)0.f,
                            (__bf16)0.f, (__bf16)0.f, (__bf16)0.f, (__bf16)0.f};
                #pragma unroll
                for (int c = 0; c < 4; ++c) {
                    int ch = p * 4 + c;
                    *(bf16x8*)((char*)xlds + s * 256 + ((ch * 16) ^ ((s & 7) << 4))) = z;
                }
            }
        }
        __syncthreads();

        #pragma unroll
        for (int rt = 0; rt < 4; ++rt) {
            bf16x8 af[4];
            int arow = rt * 16 + (lane & 15);
            #pragma unroll
            for (int ks = 0; ks < 4; ++ks) {
                int k0 = ks * 32 + (lane >> 4) * 8;
                af[ks] = *(const bf16x8*)((const char*)xlds + arow * 256 + ((k0 * 2) ^ ((arow & 7) << 4)));
            }
            f32x4 acc[2];
            acc[0] = (f32x4){0.f, 0.f, 0.f, 0.f};
            acc[1] = (f32x4){0.f, 0.f, 0.f, 0.f};
            #pragma unroll
            for (int ks = 0; ks < 4; ++ks) {
                acc[0] = __builtin_amdgcn_mfma_f32_16x16x32_bf16(bfr[0][ks], af[ks], acc[0], 0, 0, 0);
                acc[1] = __builtin_amdgcn_mfma_f32_16x16x32_bf16(bfr[1][ks], af[ks], acc[1], 0, 0, 0);
            }
            int srow = rt * 16 + (lane & 15);
            if (srow < cnt) {
                int d = dlds[srow];
                #pragma unroll
                for (int n2 = 0; n2 < 2; ++n2) {
                    float* hp = hout + (size_t)d * 128 + w * 32 + n2 * 16 + ((lane >> 4) << 2);
                    #pragma unroll
                    for (int reg = 0; reg < 4; ++reg) atomicAdd(hp + reg, acc[n2][reg]);
                }
            }
        }
    }
}

// ------------------------------------------------------------------ launch
extern "C" void kernel_launch(void* const* d_in, const int* in_sizes, int n_in,
                              void* d_out, int out_size, void* d_ws, size_t ws_size,
                              hipStream_t stream) {
    const int*   src   = (const int*)  d_in[1];
    const int*   dst   = (const int*)  d_in[2];
    const int*   etype = (const int*)  d_in[3];
    const float* norm  = (const float*)d_in[4];
    const float* emb   = (const float*)d_in[6];
    const float* V1    = (const float*)d_in[7];
    const float* comp1 = (const float*)d_in[8];
    const float* loop1 = (const float*)d_in[9];
    const float* bias1 = (const float*)d_in[10];
    const float* V2    = (const float*)d_in[11];
    const float* comp2 = (const float*)d_in[12];
    const float* loop2 = (const float*)d_in[13];
    const float* bias2 = (const float*)d_in[14];
    float* out = (float*)d_out;

    char* ws = (char*)d_ws;
    size_t off = 0;
    auto carve = [&](size_t bytes) -> void* {
        void* p = ws + off;
        off += (bytes + 255) & ~(size_t)255;
        return p;
    };
    const size_t WB = (size_t)N_RELS * 16384 * 2;                 // 7.77 MB
    u16* Wbt1      = (u16*)carve(WB);
    u16* Wbt2      = (u16*)carve(WB);
    float* h1      = (float*)carve((size_t)N_NODES * 128 * 4);    // 7.68 MB
    int*  perm     = (int*)carve((size_t)N_EDGES * 4);
    int*  srcPerm  = (int*)carve((size_t)N_EDGES * 4);
    float* normPerm= (float*)carve((size_t)N_EDGES * 4);
    int*  blockHist= (int*)carve((size_t)N_RELS * NB_SORT * 4);
    int*  baseOff  = (int*)carve((size_t)N_RELS * NB_SORT * 4);
    int2* tiles    = (int2*)carve((size_t)NT_MAX * 8);
    int*  tileCnt  = (int*)carve(256);
    u16*  lwT1     = (u16*)carve(128 * 128 * 2);
    u16*  lwT2     = (u16*)carve(128 * 128 * 2);
    u16*  compbf1  = (u16*)carve(256 * 128 * 2);
    u16*  compbf2  = (u16*)carve(256 * 128 * 2);
    u16*  aimg     = (u16*)carve((size_t)16384 * 128 * 2);        // 4 MB
    int*  deg      = (int*)carve((size_t)N_NODES * 4);
    int*  rowptr   = (int*)carve((size_t)(N_NODES + 1) * 4);
    int*  cursor   = (int*)carve((size_t)(N_NODES + 1) * 4);
    int*  dstSlots = (int*)carve((size_t)N_EDGES * 4);
    u16*  xbf      = (u16*)carve((size_t)N_NODES * 128 * 2);      // 3.84 MB
    u16*  msg      = (u16*)carve((size_t)N_EDGES * 128 * 2);      // 102.4 MB
    bool twoPhase = (off <= ws_size);                             // call-invariant

    // ---- sort edges by relation (shared by both layers), contention-free
    histA_kernel<<<NB_SORT, 256, 0, stream>>>(etype, blockHist);
    scanB_kernel<<<1, 256, 0, stream>>>(blockHist, baseOff, tiles, tileCnt);
    scatterC_kernel<<<NB_SORT, 256, 0, stream>>>(etype, src, norm, baseOff,
                                                 perm, srcPerm, normPerm);

    if (twoPhase) {
        // ---- dst-CSR (slot lists per destination node)
        zeroDeg_kernel<<<59, 256, 0, stream>>>(deg);
        degcnt_kernel<<<391, 256, 0, stream>>>(dst, deg);
        scanDeg_kernel<<<1, 256, 0, stream>>>(deg, rowptr, cursor);
        scatterDst_kernel<<<391, 256, 0, stream>>>(dst, perm, cursor, dstSlots);
    }

    // ---- per-relation weights: Wbt = comp @ aimg (MFMA, direct W^T image)
    dim3 wgg(4, 128);
    compcast_kernel<<<128, 256, 0, stream>>>(comp1, compbf1);
    compcast_kernel<<<128, 256, 0, stream>>>(comp2, compbf2);
    vt_kernel<<<128, 256, 0, stream>>>(V1, aimg);
    wgemmT_kernel<<<wgg, 256, 0, stream>>>(compbf1, aimg, Wbt1);
    vt_kernel<<<128, 256, 0, stream>>>(V2, aimg);
    wgemmT_kernel<<<wgg, 256, 0, stream>>>(compbf2, aimg, Wbt2);
    loopT_kernel<<<1, 256, 0, stream>>>(loop1, lwT1);
    loopT_kernel<<<1, 256, 0, stream>>>(loop2, lwT2);

    if (twoPhase) {
        // ---- layer 1
        xbf_kernel<<<938, 256, 0, stream>>>(emb, xbf, 0);
        init_mfma_kernel<<<235, 256, 0, stream>>>(emb, lwT1, bias1, h1, 0);
        msg_kernel<<<NT_MAX, 256, 0, stream>>>(xbf, srcPerm, tiles, tileCnt,
                                               Wbt1, msg);
        reduce_kernel<<<3750, 256, 0, stream>>>((const u32*)msg, normPerm,
                                                rowptr, dstSlots, h1);
        // ---- layer 2
        xbf_kernel<<<938, 256, 0, stream>>>(h1, xbf, 1);
        init_mfma_kernel<<<235, 256, 0, stream>>>(h1, lwT2, bias2, out, 1);
        msg_kernel<<<NT_MAX, 256, 0, stream>>>(xbf, srcPerm, tiles, tileCnt,
                                               Wbt2, msg);
        reduce_kernel<<<3750, 256, 0, stream>>>((const u32*)msg, normPerm,
                                                rowptr, dstSlots, out);
    } else {
        // ---- fallback: fused atomic scatter (small workspace)
        init_mfma_kernel<<<235, 256, 0, stream>>>(emb, lwT1, bias1, h1, 0);
        edge_atomic_kernel<<<NT_MAX, 256, 0, stream>>>(emb, src, dst, norm, perm, tiles,
                                                       tileCnt, Wbt1, h1, 0);
        init_mfma_kernel<<<235, 256, 0, stream>>>(h1, lwT2, bias2, out, 1);
        edge_atomic_kernel<<<NT_MAX, 256, 0, stream>>>(h1, src, dst, norm, perm, tiles,
                                                       tileCnt, Wbt2, out, 1);
    }
}

// Round 10
// 397.718 us; speedup vs baseline: 1.6372x; 1.0396x over previous
//
#include <hip/hip_runtime.h>
#include <hip/hip_bf16.h>

// RGCN 2-layer forward, MI355X.
// Two-phase edge flow: msg_kernel (double-buffered LDS pipeline) writes
// unscaled bf16 message rows x@W_r; reduce_kernel sums norm_e * msg_e per
// dst node via a dst-CSR (one wave per node, 4-deep ILP) and can emit the
// next layer's bf16 relu'd x image. Per-relation W^T image built by one
// bf16 MFMA GEMM. Edges counting-sorted by etype; XCD-aware tile swizzle.
// Fallback atomic path if d_ws is too small for the 102 MB message buffer.

typedef unsigned short u16;
typedef unsigned int   u32;
typedef __bf16 bf16x8 __attribute__((ext_vector_type(8)));
typedef float  f32x4  __attribute__((ext_vector_type(4)));
typedef u32    u32x2  __attribute__((ext_vector_type(2)));

#define N_NODES 15000
#define N_EDGES 400000
#define N_RELS  237
#define N_BASES 100
#define NT_MAX  1800   // 8 * 225, >= sum ceil(n_r/256) (max 1799)
#define NB_SORT 196    // sort chunks
#define CHUNK   2048   // NB_SORT*CHUNK = 401408 >= N_EDGES

__device__ __forceinline__ u32 packbf(float a, float b) {
    u16 lo = __builtin_bit_cast(u16, (__bf16)a);
    u16 hi = __builtin_bit_cast(u16, (__bf16)b);
    return (u32)lo | ((u32)hi << 16);
}
__device__ __forceinline__ u16 bf16bits(float a) {
    return __builtin_bit_cast(u16, (__bf16)a);
}
__device__ __forceinline__ float bfbits2f(u32 hi16) {   // hi16 in low 16 bits
    u32 x = hi16 << 16;
    return __builtin_bit_cast(float, x);
}

// -------------------------------------------------- pass A: block histogram
__global__ __launch_bounds__(256) void histA_kernel(const int* __restrict__ etype,
                                                    int* __restrict__ blockHist) {
    __shared__ int hh[256];
    int tid = threadIdx.x, b = blockIdx.x;
    hh[tid] = 0;
    __syncthreads();
    int e0 = b * CHUNK;
    int e1 = e0 + CHUNK; if (e1 > N_EDGES) e1 = N_EDGES;
    for (int e = e0 + tid; e < e1; e += 256)
        atomicAdd(&hh[etype[e]], 1);
    __syncthreads();
    if (tid < N_RELS) blockHist[tid * NB_SORT + b] = hh[tid];
}

// ------------------- pass B: totals, prefix, tiles, per-block base offsets
__global__ __launch_bounds__(256) void scanB_kernel(const int* __restrict__ blockHist,
                                                    int* __restrict__ baseOff,
                                                    int2* __restrict__ tiles,
                                                    int* __restrict__ tileCount) {
    __shared__ int h[256], o[256], to[256];
    int tid = threadIdx.x;
    int sum = 0;
    if (tid < N_RELS)
        for (int b = 0; b < NB_SORT; ++b) sum += blockHist[tid * NB_SORT + b];
    h[tid] = (tid < N_RELS) ? sum : 0;
    __syncthreads();
    if (tid == 0) {
        int run = 0, tc = 0;
        for (int r = 0; r < N_RELS; ++r) {
            o[r] = run; run += h[r];
            to[r] = tc; tc += (h[r] + 255) >> 8;
        }
        *tileCount = tc;
    }
    __syncthreads();
    if (tid < N_RELS) {
        int n = h[tid], t0 = to[tid], base = o[tid];
        for (int t = 0; t * 256 < n; ++t) {
            int nE = n - t * 256; if (nE > 256) nE = 256;
            tiles[t0 + t] = make_int2(base + t * 256, (tid << 9) | nE);
        }
        int run = base;
        for (int b = 0; b < NB_SORT; ++b) {
            baseOff[tid * NB_SORT + b] = run;
            run += blockHist[tid * NB_SORT + b];
        }
    }
}

// ----------- pass C: scatter with LDS cursors; also emit srcPerm/normPerm
__global__ __launch_bounds__(256) void scatterC_kernel(const int* __restrict__ etype,
                                                       const int* __restrict__ src,
                                                       const float* __restrict__ norm,
                                                       const int* __restrict__ baseOff,
                                                       int* __restrict__ perm,
                                                       int* __restrict__ srcPerm,
                                                       float* __restrict__ normPerm) {
    __shared__ int lcur[256];
    int tid = threadIdx.x, b = blockIdx.x;
    if (tid < N_RELS) lcur[tid] = baseOff[tid * NB_SORT + b];
    __syncthreads();
    int e0 = b * CHUNK;
    int e1 = e0 + CHUNK; if (e1 > N_EDGES) e1 = N_EDGES;
    for (int e = e0 + tid; e < e1; e += 256) {
        int r = etype[e];
        int pos = atomicAdd(&lcur[r], 1);
        perm[pos] = e;
        srcPerm[pos] = src[e];
        normPerm[pos] = norm[e];
    }
}

// ----------------------------------------- dst-CSR build (for reduce pass)
__global__ __launch_bounds__(256) void zeroDeg_kernel(int* __restrict__ deg) {
    int i = blockIdx.x * 256 + threadIdx.x;
    if (i < N_NODES) deg[i] = 0;
}
__global__ __launch_bounds__(256) void degcnt_kernel(const int* __restrict__ dst,
                                                     int* __restrict__ deg) {
    for (int e = blockIdx.x * 256 + threadIdx.x; e < N_EDGES; e += gridDim.x * 256)
        atomicAdd(&deg[dst[e]], 1);
}
__global__ __launch_bounds__(256) void scanDeg_kernel(const int* __restrict__ deg,
                                                      int* __restrict__ rowptr,
                                                      int* __restrict__ cursor) {
    __shared__ int part[256];
    int tid = threadIdx.x;
    const int R = 59;                       // 256*59 = 15104 >= 15001
    int lo = tid * R, hi = lo + R; if (hi > N_NODES + 1) hi = N_NODES + 1;
    int s = 0;
    for (int i = lo; i < hi; ++i) s += (i < N_NODES) ? deg[i] : 0;
    part[tid] = s;
    __syncthreads();
    if (tid == 0) {
        int run = 0;
        for (int t = 0; t < 256; ++t) { int tmp = part[t]; part[t] = run; run += tmp; }
    }
    __syncthreads();
    int run = part[tid];
    for (int i = lo; i < hi; ++i) {
        rowptr[i] = run; cursor[i] = run;
        run += (i < N_NODES) ? deg[i] : 0;
    }
}
__global__ __launch_bounds__(256) void scatterDst_kernel(const int* __restrict__ dst,
                                                         const int* __restrict__ perm,
                                                         int* __restrict__ cursor,
                                                         int* __restrict__ dstSlots) {
    for (int s = blockIdx.x * 256 + threadIdx.x; s < N_EDGES; s += gridDim.x * 256) {
        int e = perm[s];
        int v = dst[e];
        int pos = atomicAdd(&cursor[v], 1);   // ~27 edges/node: low contention
        dstSlots[pos] = s;
    }
}

// ------------------------- comp (fp32 [237][100]) -> bf16 [256][128] padded
__global__ __launch_bounds__(256) void compcast_kernel(const float* __restrict__ comp,
                                                       u16* __restrict__ compbf) {
    int idx = blockIdx.x * 256 + threadIdx.x;    // 32768 total
    if (idx >= 256 * 128) return;
    int r = idx >> 7, b = idx & 127;
    float v = (r < N_RELS && b < N_BASES) ? comp[(size_t)r * N_BASES + b] : 0.f;
    compbf[idx] = bf16bits(v);
}

// ------ V (fp32 [100][128][128]) -> aimg bf16: aimg[(col*128+k)*128 + b]
// = V[b][k][col]; rows b>=100 zeroed. One block per k; LDS transpose.
__global__ __launch_bounds__(256) void vt_kernel(const float* __restrict__ V,
                                                 u16* __restrict__ aimg) {
    __shared__ u16 t[128 * 130];      // [col][b] padded
    int k = blockIdx.x, tid = threadIdx.x;
    #pragma unroll
    for (int i = 0; i < 64; ++i) {
        int idx = i * 256 + tid;      // b = idx>>7, col = idx&127
        int b = idx >> 7, col = idx & 127;
        float v = (b < N_BASES) ? V[(size_t)b * 16384 + k * 128 + col] : 0.f;
        t[col * 130 + b] = bf16bits(v);
    }
    __syncthreads();
    #pragma unroll
    for (int i = 0; i < 64; ++i) {
        int idx = i * 256 + tid;      // col = idx>>7, b = idx&127
        int col = idx >> 7, b = idx & 127;
        aimg[((size_t)col * 128 + k) * 128 + b] = t[col * 130 + b];
    }
}

// ---------- Wbt[r][j] = sum_b comp[r][b] * aimg[j][b]   (MFMA, j=col*128+k)
__global__ __launch_bounds__(256) void wgemmT_kernel(const u16* __restrict__ compbf,
                                                     const u16* __restrict__ aimg,
                                                     u16* __restrict__ Wbt) {
    __shared__ u16 clds[8192];        // 64 rows x 128 k swizzled
    int m0 = blockIdx.x * 64, n0 = blockIdx.y * 128;
    int tid = threadIdx.x, lane = tid & 63, w = tid >> 6;

    bf16x8 afr[2][4];
    #pragma unroll
    for (int n2 = 0; n2 < 2; ++n2) {
        int j = n0 + w * 32 + n2 * 16 + (lane & 15);
        #pragma unroll
        for (int ks = 0; ks < 4; ++ks) {
            int b0 = ks * 32 + (lane >> 4) * 8;
            afr[n2][ks] = *(const bf16x8*)(aimg + (size_t)j * 128 + b0);
        }
    }
    {
        int s = tid >> 2, p = tid & 3;
        const uint4* cr = (const uint4*)(compbf + (size_t)(m0 + s) * 128);
        #pragma unroll
        for (int c = 0; c < 4; ++c) {
            int ch = p * 4 + c;
            *(uint4*)((char*)clds + s * 256 + ((ch * 16) ^ ((s & 7) << 4))) = cr[ch];
        }
    }
    __syncthreads();

    #pragma unroll
    for (int rt = 0; rt < 4; ++rt) {
        bf16x8 cf[4];
        int arow = rt * 16 + (lane & 15);
        #pragma unroll
        for (int ks = 0; ks < 4; ++ks) {
            int k0 = ks * 32 + (lane >> 4) * 8;
            cf[ks] = *(const bf16x8*)((const char*)clds + arow * 256 + ((k0 * 2) ^ ((arow & 7) << 4)));
        }
        f32x4 acc[2];
        acc[0] = (f32x4){0.f, 0.f, 0.f, 0.f};
        acc[1] = (f32x4){0.f, 0.f, 0.f, 0.f};
        #pragma unroll
        for (int ks = 0; ks < 4; ++ks) {
            acc[0] = __builtin_amdgcn_mfma_f32_16x16x32_bf16(afr[0][ks], cf[ks], acc[0], 0, 0, 0);
            acc[1] = __builtin_amdgcn_mfma_f32_16x16x32_bf16(afr[1][ks], cf[ks], acc[1], 0, 0, 0);
        }
        int r = m0 + rt * 16 + (lane & 15);
        if (r < N_RELS) {
            #pragma unroll
            for (int n2 = 0; n2 < 2; ++n2) {
                int jb = n0 + w * 32 + n2 * 16 + ((lane >> 4) << 2);
                u32x2 pk;
                pk.x = packbf(acc[n2][0], acc[n2][1]);
                pk.y = packbf(acc[n2][2], acc[n2][3]);
                *(u32x2*)(Wbt + (size_t)r * 16384 + jb) = pk;
            }
        }
    }
}

// ---------- loop_w (fp32 RM [k][n]) -> bf16 col-major W^T image (linear)
__global__ __launch_bounds__(256) void loopT_kernel(const float* __restrict__ lw,
                                                    u16* __restrict__ outT) {
    int idx = blockIdx.x * 256 + threadIdx.x;   // 8192 uints
    if (idx >= 8192) return;
    int col = idx >> 6, kk2 = idx & 63;
    float a = lw[(size_t)(2 * kk2) * 128 + col];
    float b = lw[(size_t)(2 * kk2 + 1) * 128 + col];
    ((u32*)outT)[col * 64 + kk2] = packbf(a, b);
}

// ------------------- x (fp32, optional relu) -> bf16 row image [v][128]
__global__ __launch_bounds__(256) void xbf_kernel(const float* __restrict__ x,
                                                  u16* __restrict__ xbf,
                                                  int reluIn) {
    int i = blockIdx.x * 256 + threadIdx.x;     // one thread = 8 features
    if (i >= N_NODES * 16) return;
    const float4* xp = (const float4*)x;
    float4 f0 = xp[i * 2], f1 = xp[i * 2 + 1];
    if (reluIn) {
        f0.x = fmaxf(f0.x, 0.f); f0.y = fmaxf(f0.y, 0.f);
        f0.z = fmaxf(f0.z, 0.f); f0.w = fmaxf(f0.w, 0.f);
        f1.x = fmaxf(f1.x, 0.f); f1.y = fmaxf(f1.y, 0.f);
        f1.z = fmaxf(f1.z, 0.f); f1.w = fmaxf(f1.w, 0.f);
    }
    uint4 pk;
    pk.x = packbf(f0.x, f0.y); pk.y = packbf(f0.z, f0.w);
    pk.z = packbf(f1.x, f1.y); pk.w = packbf(f1.z, f1.w);
    ((uint4*)xbf)[i] = pk;
}

// ------------- h = bias + f(x) @ loop_w  (MFMA, consecutive rows, f=relu)
__global__ __launch_bounds__(256) void init_mfma_kernel(const float* __restrict__ xin,
                                                        const u16* __restrict__ lwT,
                                                        const float* __restrict__ bias,
                                                        float* __restrict__ hout,
                                                        int reluIn) {
    __shared__ u16 xlds[8192];    // 16KB: [s][k] swizzled, 64 rows
    int v0 = blockIdx.x * 64;
    int tid = threadIdx.x, lane = tid & 63, w = tid >> 6;

    bf16x8 bfr[2][4];
    #pragma unroll
    for (int n2 = 0; n2 < 2; ++n2) {
        int col = w * 32 + n2 * 16 + (lane & 15);
        #pragma unroll
        for (int ks = 0; ks < 4; ++ks) {
            int k0 = ks * 32 + (lane >> 4) * 8;
            bfr[n2][ks] = *(const bf16x8*)(lwT + (size_t)col * 128 + k0);
        }
    }

    {
        int s = tid >> 2, p = tid & 3;
        int row = v0 + s;
        if (row < N_NODES) {
            const float4* xr = (const float4*)(xin + (size_t)row * 128 + p * 32);
            #pragma unroll
            for (int c = 0; c < 4; ++c) {
                float4 f0 = xr[c * 2], f1 = xr[c * 2 + 1];
                if (reluIn) {
                    f0.x = fmaxf(f0.x, 0.f); f0.y = fmaxf(f0.y, 0.f);
                    f0.z = fmaxf(f0.z, 0.f); f0.w = fmaxf(f0.w, 0.f);
                    f1.x = fmaxf(f1.x, 0.f); f1.y = fmaxf(f1.y, 0.f);
                    f1.z = fmaxf(f1.z, 0.f); f1.w = fmaxf(f1.w, 0.f);
                }
                bf16x8 pk;
                pk[0] = (__bf16)f0.x; pk[1] = (__bf16)f0.y;
                pk[2] = (__bf16)f0.z; pk[3] = (__bf16)f0.w;
                pk[4] = (__bf16)f1.x; pk[5] = (__bf16)f1.y;
                pk[6] = (__bf16)f1.z; pk[7] = (__bf16)f1.w;
                int ch = p * 4 + c;
                *(bf16x8*)((char*)xlds + s * 256 + ((ch * 16) ^ ((s & 7) << 4))) = pk;
            }
        } else {
            bf16x8 z = {(__bf16)0.f, (__bf16)0.f, (__bf16)0.f, (__bf16)0.f,
                        (__bf16)0.f, (__bf16)0.f, (__bf16)0.f, (__bf16)0.f};
            #pragma unroll
            for (int c = 0; c < 4; ++c) {
                int ch = p * 4 + c;
                *(bf16x8*)((char*)xlds + s * 256 + ((ch * 16) ^ ((s & 7) << 4))) = z;
            }
        }
    }
    __syncthreads();

    #pragma unroll
    for (int rt = 0; rt < 4; ++rt) {
        bf16x8 af[4];
        int arow = rt * 16 + (lane & 15);
        #pragma unroll
        for (int ks = 0; ks < 4; ++ks) {
            int k0 = ks * 32 + (lane >> 4) * 8;
            af[ks] = *(const bf16x8*)((const char*)xlds + arow * 256 + ((k0 * 2) ^ ((arow & 7) << 4)));
        }
        f32x4 acc[2];
        acc[0] = (f32x4){0.f, 0.f, 0.f, 0.f};
        acc[1] = (f32x4){0.f, 0.f, 0.f, 0.f};
        #pragma unroll
        for (int ks = 0; ks < 4; ++ks) {
            acc[0] = __builtin_amdgcn_mfma_f32_16x16x32_bf16(bfr[0][ks], af[ks], acc[0], 0, 0, 0);
            acc[1] = __builtin_amdgcn_mfma_f32_16x16x32_bf16(bfr[1][ks], af[ks], acc[1], 0, 0, 0);
        }
        int orow = v0 + rt * 16 + (lane & 15);
        if (orow < N_NODES) {
            #pragma unroll
            for (int n2 = 0; n2 < 2; ++n2) {
                int fbase = w * 32 + n2 * 16 + ((lane >> 4) << 2);
                float4 bv = *(const float4*)(bias + fbase);
                float4 o;
                o.x = acc[n2][0] + bv.x; o.y = acc[n2][1] + bv.y;
                o.z = acc[n2][2] + bv.z; o.w = acc[n2][3] + bv.w;
                *(float4*)(hout + (size_t)orow * 128 + fbase) = o;
            }
        }
    }
}

// ---------------- phase 1: per-edge messages msg[slot] = xbf[src] @ W_r
// Double-buffered LDS pipeline: gather subtile t+1 into regs BEFORE the
// MFMA of subtile t, write regs->LDS after the barrier (global latency
// hides under compute). XCD-aware tile swizzle; SWAPPED mfma(bf, af).
__global__ __launch_bounds__(256) void msg_kernel(const u16* __restrict__ xbf,
                                                  const int* __restrict__ srcPerm,
                                                  const int2* __restrict__ tiles,
                                                  const int* __restrict__ tileCount,
                                                  const u16* __restrict__ WbtT,
                                                  u16* __restrict__ msg) {
    __shared__ u16 xlds[2][8192];    // 2 x 16KB: [s][k] swizzled
    int bid = blockIdx.x;
    int tile = (bid & 7) * (NT_MAX / 8) + (bid >> 3);   // XCD-contiguous
    if (tile >= *tileCount) return;
    int2 td = tiles[tile];
    int slot0 = td.x;
    int r  = td.y >> 9;
    int nE = td.y & 511;
    int tid = threadIdx.x, lane = tid & 63, w = tid >> 6;
    int gs = tid >> 2, gp = tid & 3;     // gather role: row gs, quarter gp

    bf16x8 bfr[2][4];
    #pragma unroll
    for (int n2 = 0; n2 < 2; ++n2) {
        int col = w * 32 + n2 * 16 + (lane & 15);
        #pragma unroll
        for (int ks = 0; ks < 4; ++ks) {
            int k0 = ks * 32 + (lane >> 4) * 8;
            bfr[n2][ks] = *(const bf16x8*)(WbtT + (size_t)r * 16384 + col * 128 + k0);
        }
    }

    uint4 g[4];
    auto gather = [&](int s0) {
        int cnt = nE - s0; if (cnt > 64) cnt = 64;
        if (gs < cnt) {
            int xrow = srcPerm[slot0 + s0 + gs];
            const uint4* xr = (const uint4*)(xbf + (size_t)xrow * 128);
            #pragma unroll
            for (int c = 0; c < 4; ++c) g[c] = xr[gp * 4 + c];
        } else {
            uint4 z = {0u, 0u, 0u, 0u};
            #pragma unroll
            for (int c = 0; c < 4; ++c) g[c] = z;
        }
    };
    auto writeLds = [&](u16* buf) {
        #pragma unroll
        for (int c = 0; c < 4; ++c) {
            int ch = gp * 4 + c;
            *(uint4*)((char*)buf + gs * 256 + ((ch * 16) ^ ((gs & 7) << 4))) = g[c];
        }
    };

    gather(0);
    writeLds(xlds[0]);
    __syncthreads();
    int cur = 0;

    for (int s0 = 0; s0 < nE; s0 += 64) {
        int cnt = nE - s0; if (cnt > 64) cnt = 64;
        int nxt = s0 + 64;
        if (nxt < nE) gather(nxt);          // issue next gather early

        const u16* buf = xlds[cur];
        #pragma unroll
        for (int rt = 0; rt < 4; ++rt) {
            bf16x8 af[4];
            int arow = rt * 16 + (lane & 15);
            #pragma unroll
            for (int ks = 0; ks < 4; ++ks) {
                int k0 = ks * 32 + (lane >> 4) * 8;
                af[ks] = *(const bf16x8*)((const char*)buf + arow * 256 + ((k0 * 2) ^ ((arow & 7) << 4)));
            }
            f32x4 acc[2];
            acc[0] = (f32x4){0.f, 0.f, 0.f, 0.f};
            acc[1] = (f32x4){0.f, 0.f, 0.f, 0.f};
            #pragma unroll
            for (int ks = 0; ks < 4; ++ks) {
                acc[0] = __builtin_amdgcn_mfma_f32_16x16x32_bf16(bfr[0][ks], af[ks], acc[0], 0, 0, 0);
                acc[1] = __builtin_amdgcn_mfma_f32_16x16x32_bf16(bfr[1][ks], af[ks], acc[1], 0, 0, 0);
            }
            int srow = rt * 16 + (lane & 15);
            if (srow < cnt) {
                int slot = slot0 + s0 + srow;
                #pragma unroll
                for (int n2 = 0; n2 < 2; ++n2) {
                    int fbase = w * 32 + n2 * 16 + ((lane >> 4) << 2);
                    u32x2 pk;
                    pk.x = packbf(acc[n2][0], acc[n2][1]);
                    pk.y = packbf(acc[n2][2], acc[n2][3]);
                    *(u32x2*)(msg + (size_t)slot * 128 + fbase) = pk;
                }
            }
        }

        if (nxt >= nE) break;
        __syncthreads();                     // all reads of xlds[cur] done
        writeLds(xlds[cur ^ 1]);
        __syncthreads();                     // next buffer visible
        cur ^= 1;
    }
}

// ------------- phase 2: per-node reduce h[v] += sum norm_e * msg_e
// Optionally emits the next layer's bf16 relu'd x image (fused xbf).
__global__ __launch_bounds__(256) void reduce_kernel(const u32* __restrict__ msg32,
                                                     const float* __restrict__ normPerm,
                                                     const int* __restrict__ rowptr,
                                                     const int* __restrict__ dstSlots,
                                                     float* __restrict__ h,
                                                     u32* __restrict__ xbfOut) {
    int v = blockIdx.x * 4 + (threadIdx.x >> 6);
    int lane = threadIdx.x & 63;
    if (v >= N_NODES) return;
    int p0 = rowptr[v], p1 = rowptr[v + 1];
    float a0 = 0.f, a1 = 0.f, b0 = 0.f, b1 = 0.f;
    int j = p0;
    for (; j + 3 < p1; j += 4) {
        int s0 = dstSlots[j], s1 = dstSlots[j + 1];
        int s2 = dstSlots[j + 2], s3 = dstSlots[j + 3];
        float n0 = normPerm[s0], n1 = normPerm[s1];
        float n2 = normPerm[s2], n3 = normPerm[s3];
        u32 m0 = __builtin_nontemporal_load(msg32 + (size_t)s0 * 64 + lane);
        u32 m1 = __builtin_nontemporal_load(msg32 + (size_t)s1 * 64 + lane);
        u32 m2 = __builtin_nontemporal_load(msg32 + (size_t)s2 * 64 + lane);
        u32 m3 = __builtin_nontemporal_load(msg32 + (size_t)s3 * 64 + lane);
        a0 += n0 * bfbits2f(m0 & 0xffffu); a1 += n0 * bfbits2f(m0 >> 16);
        b0 += n1 * bfbits2f(m1 & 0xffffu); b1 += n1 * bfbits2f(m1 >> 16);
        a0 += n2 * bfbits2f(m2 & 0xffffu); a1 += n2 * bfbits2f(m2 >> 16);
        b0 += n3 * bfbits2f(m3 & 0xffffu); b1 += n3 * bfbits2f(m3 >> 16);
    }
    for (; j < p1; ++j) {
        int s0 = dstSlots[j];
        float n0 = normPerm[s0];
        u32 m0 = __builtin_nontemporal_load(msg32 + (size_t)s0 * 64 + lane);
        a0 += n0 * bfbits2f(m0 & 0xffffu); a1 += n0 * bfbits2f(m0 >> 16);
    }
    float2 hv = *(float2*)(h + (size_t)v * 128 + lane * 2);
    hv.x += a0 + b0;
    hv.y += a1 + b1;
    *(float2*)(h + (size_t)v * 128 + lane * 2) = hv;
    if (xbfOut) {
        float rx = fmaxf(hv.x, 0.f), ry = fmaxf(hv.y, 0.f);
        xbfOut[(size_t)v * 64 + lane] = packbf(rx, ry);
    }
}

// ------------------- fallback: fused edge GEMM + fp32 atomic scatter
__global__ __launch_bounds__(256) void edge_atomic_kernel(const float* __restrict__ x,
                                                          const int* __restrict__ src,
                                                          const int* __restrict__ dst,
                                                          const float* __restrict__ norm,
                                                          const int* __restrict__ perm,
                                                          const int2* __restrict__ tiles,
                                                          const int* __restrict__ tileCount,
                                                          const u16* __restrict__ WbtT,
                                                          float* __restrict__ hout,
                                                          int reluIn) {
    __shared__ u16 xlds[8192];
    __shared__ int dlds[64];
    int bid = blockIdx.x;
    if (bid >= *tileCount) return;
    int2 td = tiles[bid];
    int slot0 = td.x;
    int r  = td.y >> 9;
    int nE = td.y & 511;
    int tid = threadIdx.x, lane = tid & 63, w = tid >> 6;

    bf16x8 bfr[2][4];
    #pragma unroll
    for (int n2 = 0; n2 < 2; ++n2) {
        int col = w * 32 + n2 * 16 + (lane & 15);
        #pragma unroll
        for (int ks = 0; ks < 4; ++ks) {
            int k0 = ks * 32 + (lane >> 4) * 8;
            bfr[n2][ks] = *(const bf16x8*)(WbtT + (size_t)r * 16384 + col * 128 + k0);
        }
    }

    for (int s0 = 0; s0 < nE; s0 += 64) {
        int cnt = nE - s0; if (cnt > 64) cnt = 64;
        __syncthreads();
        {
            int s = tid >> 2, p = tid & 3;
            if (s < cnt) {
                int e = perm[slot0 + s0 + s];
                int xrow = src[e];
                float nm = norm[e];
                if (p == 0) dlds[s] = dst[e];
                const float4* xr = (const float4*)(x + (size_t)xrow * 128 + p * 32);
                #pragma unroll
                for (int c = 0; c < 4; ++c) {
                    float4 f0 = xr[c * 2], f1 = xr[c * 2 + 1];
                    if (reluIn) {
                        f0.x = fmaxf(f0.x, 0.f); f0.y = fmaxf(f0.y, 0.f);
                        f0.z = fmaxf(f0.z, 0.f); f0.w = fmaxf(f0.w, 0.f);
                        f1.x = fmaxf(f1.x, 0.f); f1.y = fmaxf(f1.y, 0.f);
                        f1.z = fmaxf(f1.z, 0.f); f1.w = fmaxf(f1.w, 0.f);
                    }
                    bf16x8 pk;
                    pk[0] = (__bf16)(f0.x * nm); pk[1] = (__bf16)(f0.y * nm);
                    pk[2] = (__bf16)(f0.z * nm); pk[3] = (__bf16)(f0.w * nm);
                    pk[4] = (__bf16)(f1.x * nm); pk[5] = (__bf16)(f1.y * nm);
                    pk[6] = (__bf16)(f1.z * nm); pk[7] = (__bf16)(f1.w * nm);
                    int ch = p * 4 + c;
                    *(bf16x8*)((char*)xlds + s * 256 + ((ch * 16) ^ ((s & 7) << 4))) = pk;
                }
            } else {
                bf16x8 z = {(__bf16)0.f, (__bf16)0.f, (__bf16)0.f, (__bf16)0.f,
                            (__bf16)0.f, (__bf16)0.f, (__bf16)0.f, (__bf16)0.f};
                #pragma unroll
                for (int c = 0; c < 4; ++c) {
                    int ch = p * 4 + c;
                    *(bf16x8*)((char*)xlds + s * 256 + ((ch * 16) ^ ((s & 7) << 4))) = z;
                }
            }
        }
        __syncthreads();

        #pragma unroll
        for (int rt = 0; rt < 4; ++rt) {
            bf16x8 af[4];
            int arow = rt * 16 + (lane & 15);
            #pragma unroll
            for (int ks = 0; ks < 4; ++ks) {
                int k0 = ks * 32 + (lane >> 4) * 8;
                af[ks] = *(const bf16x8*)((const char*)xlds + arow * 256 + ((k0 * 2) ^ ((arow & 7) << 4)));
            }
            f32x4 acc[2];
            acc[0] = (f32x4){0.f, 0.f, 0.f, 0.f};
            acc[1] = (f32x4){0.f, 0.f, 0.f, 0.f};
            #pragma unroll
            for (int ks = 0; ks < 4; ++ks) {
                acc[0] = __builtin_amdgcn_mfma_f32_16x16x32_bf16(bfr[0][ks], af[ks], acc[0], 0, 0, 0);
                acc[1] = __builtin_amdgcn_mfma_f32_16x16x32_bf16(bfr[1][ks], af[ks], acc[1], 0, 0, 0);
            }
            int srow = rt * 16 + (lane & 15);
            if (srow < cnt) {
                int d = dlds[srow];
                #pragma unroll
                for (int n2 = 0; n2 < 2; ++n2) {
                    float* hp = hout + (size_t)d * 128 + w * 32 + n2 * 16 + ((lane >> 4) << 2);
                    #pragma unroll
                    for (int reg = 0; reg < 4; ++reg) atomicAdd(hp + reg, acc[n2][reg]);
                }
            }
        }
    }
}

// ------------------------------------------------------------------ launch
extern "C" void kernel_launch(void* const* d_in, const int* in_sizes, int n_in,
                              void* d_out, int out_size, void* d_ws, size_t ws_size,
                              hipStream_t stream) {
    const int*   src   = (const int*)  d_in[1];
    const int*   dst   = (const int*)  d_in[2];
    const int*   etype = (const int*)  d_in[3];
    const float* norm  = (const float*)d_in[4];
    const float* emb   = (const float*)d_in[6];
    const float* V1    = (const float*)d_in[7];
    const float* comp1 = (const float*)d_in[8];
    const float* loop1 = (const float*)d_in[9];
    const float* bias1 = (const float*)d_in[10];
    const float* V2    = (const float*)d_in[11];
    const float* comp2 = (const float*)d_in[12];
    const float* loop2 = (const float*)d_in[13];
    const float* bias2 = (const float*)d_in[14];
    float* out = (float*)d_out;

    char* ws = (char*)d_ws;
    size_t off = 0;
    auto carve = [&](size_t bytes) -> void* {
        void* p = ws + off;
        off += (bytes + 255) & ~(size_t)255;
        return p;
    };
    const size_t WB = (size_t)N_RELS * 16384 * 2;                 // 7.77 MB
    u16* Wbt1      = (u16*)carve(WB);
    u16* Wbt2      = (u16*)carve(WB);
    float* h1      = (float*)carve((size_t)N_NODES * 128 * 4);    // 7.68 MB
    int*  perm     = (int*)carve((size_t)N_EDGES * 4);
    int*  srcPerm  = (int*)carve((size_t)N_EDGES * 4);
    float* normPerm= (float*)carve((size_t)N_EDGES * 4);
    int*  blockHist= (int*)carve((size_t)N_RELS * NB_SORT * 4);
    int*  baseOff  = (int*)carve((size_t)N_RELS * NB_SORT * 4);
    int2* tiles    = (int2*)carve((size_t)NT_MAX * 8);
    int*  tileCnt  = (int*)carve(256);
    u16*  lwT1     = (u16*)carve(128 * 128 * 2);
    u16*  lwT2     = (u16*)carve(128 * 128 * 2);
    u16*  compbf1  = (u16*)carve(256 * 128 * 2);
    u16*  compbf2  = (u16*)carve(256 * 128 * 2);
    u16*  aimg     = (u16*)carve((size_t)16384 * 128 * 2);        // 4 MB
    int*  deg      = (int*)carve((size_t)N_NODES * 4);
    int*  rowptr   = (int*)carve((size_t)(N_NODES + 1) * 4);
    int*  cursor   = (int*)carve((size_t)(N_NODES + 1) * 4);
    int*  dstSlots = (int*)carve((size_t)N_EDGES * 4);
    u16*  xbf      = (u16*)carve((size_t)N_NODES * 128 * 2);      // 3.84 MB
    u16*  msg      = (u16*)carve((size_t)N_EDGES * 128 * 2);      // 102.4 MB
    bool twoPhase = (off <= ws_size);                             // call-invariant

    // ---- sort edges by relation (shared by both layers), contention-free
    histA_kernel<<<NB_SORT, 256, 0, stream>>>(etype, blockHist);
    scanB_kernel<<<1, 256, 0, stream>>>(blockHist, baseOff, tiles, tileCnt);
    scatterC_kernel<<<NB_SORT, 256, 0, stream>>>(etype, src, norm, baseOff,
                                                 perm, srcPerm, normPerm);

    if (twoPhase) {
        // ---- dst-CSR (slot lists per destination node)
        zeroDeg_kernel<<<59, 256, 0, stream>>>(deg);
        degcnt_kernel<<<391, 256, 0, stream>>>(dst, deg);
        scanDeg_kernel<<<1, 256, 0, stream>>>(deg, rowptr, cursor);
        scatterDst_kernel<<<391, 256, 0, stream>>>(dst, perm, cursor, dstSlots);
    }

    // ---- per-relation weights: Wbt = comp @ aimg (MFMA, direct W^T image)
    dim3 wgg(4, 128);
    compcast_kernel<<<128, 256, 0, stream>>>(comp1, compbf1);
    compcast_kernel<<<128, 256, 0, stream>>>(comp2, compbf2);
    vt_kernel<<<128, 256, 0, stream>>>(V1, aimg);
    wgemmT_kernel<<<wgg, 256, 0, stream>>>(compbf1, aimg, Wbt1);
    vt_kernel<<<128, 256, 0, stream>>>(V2, aimg);
    wgemmT_kernel<<<wgg, 256, 0, stream>>>(compbf2, aimg, Wbt2);
    loopT_kernel<<<32, 256, 0, stream>>>(loop1, lwT1);
    loopT_kernel<<<32, 256, 0, stream>>>(loop2, lwT2);

    if (twoPhase) {
        // ---- layer 1
        xbf_kernel<<<938, 256, 0, stream>>>(emb, xbf, 0);
        init_mfma_kernel<<<235, 256, 0, stream>>>(emb, lwT1, bias1, h1, 0);
        msg_kernel<<<NT_MAX, 256, 0, stream>>>(xbf, srcPerm, tiles, tileCnt,
                                               Wbt1, msg);
        reduce_kernel<<<3750, 256, 0, stream>>>((const u32*)msg, normPerm,
                                                rowptr, dstSlots, h1, (u32*)xbf);
        // ---- layer 2 (xbf for layer 2 was fused into reduce above)
        init_mfma_kernel<<<235, 256, 0, stream>>>(h1, lwT2, bias2, out, 1);
        msg_kernel<<<NT_MAX, 256, 0, stream>>>(xbf, srcPerm, tiles, tileCnt,
                                               Wbt2, msg);
        reduce_kernel<<<3750, 256, 0, stream>>>((const u32*)msg, normPerm,
                                                rowptr, dstSlots, out, (u32*)0);
    } else {
        // ---- fallback: fused atomic scatter (small workspace)
        init_mfma_kernel<<<235, 256, 0, stream>>>(emb, lwT1, bias1, h1, 0);
        edge_atomic_kernel<<<NT_MAX, 256, 0, stream>>>(emb, src, dst, norm, perm, tiles,
                                                       tileCnt, Wbt1, h1, 0);
        init_mfma_kernel<<<235, 256, 0, stream>>>(h1, lwT2, bias2, out, 1);
        edge_atomic_kernel<<<NT_MAX, 256, 0, stream>>>(h1, src, dst, norm, perm, tiles,
                                                       tileCnt, Wbt2, out, 1);
    }
}